// Round 5
// baseline (379.949 us; speedup 1.0000x reference)
//
#include <hip/hip_runtime.h>
#include <hip/hip_bf16.h>
#include <math.h>

#define NN 20000
#define NE 320000
#define DIM 512
#define LN_EPS 1e-5f
#define NEG_SLOPE 0.2f

typedef __attribute__((ext_vector_type(8))) short bf16x8;
typedef __attribute__((ext_vector_type(4))) float f32x4;
typedef __attribute__((ext_vector_type(4))) unsigned int u32x4;

__device__ inline void gload_lds16(const void* g, void* l) {
    __builtin_amdgcn_global_load_lds(
        (const __attribute__((address_space(1))) void*)g,
        (__attribute__((address_space(3))) void*)l, 16, 0, 0);
}

__device__ inline short f2bf(float f) {
    __hip_bfloat16 b = __float2bfloat16(f);
    return *reinterpret_cast<short*>(&b);
}

// ---------------- CSR build (edge_index arrives as int32: [src(E), dst(E)]) ----------------

__global__ void count_k(const int* __restrict__ dst, int* __restrict__ cnt) {
    int e = blockIdx.x * blockDim.x + threadIdx.x;
    if (e < NE) {
        int d = dst[e];
        d = (d < 0) ? 0 : (d >= NN ? NN - 1 : d);
        atomicAdd(&cnt[d], 1);
    }
}

__global__ __launch_bounds__(1024) void scan_k(const int* __restrict__ cnt,
                                               int* __restrict__ off,
                                               int* __restrict__ cur) {
    __shared__ int s[1024];
    const int t = threadIdx.x;
    const int lo = t * 20;
    int loc[20];
    int sum = 0;
#pragma unroll
    for (int i = 0; i < 20; i++) {
        int idx = lo + i;
        int v = (idx < NN) ? cnt[idx] : 0;
        loc[i] = v; sum += v;
    }
    s[t] = sum;
    __syncthreads();
    for (int o = 1; o < 1024; o <<= 1) {
        int x = (t >= o) ? s[t - o] : 0;
        __syncthreads();
        s[t] += x;
        __syncthreads();
    }
    int run = s[t] - sum;  // exclusive prefix
#pragma unroll
    for (int i = 0; i < 20; i++) {
        int idx = lo + i;
        if (idx < NN) { off[idx] = run; cur[idx] = run; run += loc[i]; }
    }
    if (t == 1023) off[NN] = s[1023];
}

__global__ void fill_k(const int* __restrict__ src, const int* __restrict__ dst,
                       int* __restrict__ cur, int* __restrict__ slot) {
    int e = blockIdx.x * blockDim.x + threadIdx.x;
    if (e < NE) {
        int d = dst[e];
        d = (d < 0) ? 0 : (d >= NN ? NN - 1 : d);
        int sv = src[e];
        sv = (sv < 0) ? 0 : (sv >= NN ? NN - 1 : sv);
        int p = atomicAdd(&cur[d], 1);
        slot[p] = sv;
    }
}

// ---------------- converts ----------------

__global__ void conv_k(const float* __restrict__ in, __hip_bfloat16* __restrict__ out, int n) {
    int i = (blockIdx.x * blockDim.x + threadIdx.x) * 4;
    if (i < n) {
        float4 v = *(const float4*)&in[i];
        out[i + 0] = __float2bfloat16(v.x);
        out[i + 1] = __float2bfloat16(v.y);
        out[i + 2] = __float2bfloat16(v.z);
        out[i + 3] = __float2bfloat16(v.w);
    }
}

// W[512][512] fp32 -> BT[n][k] bf16 (transpose); z selects (W1->B1, W2->B2)
__global__ __launch_bounds__(256) void convT_k(const float* __restrict__ W1f,
                                               const float* __restrict__ W2f,
                                               __hip_bfloat16* __restrict__ B1,
                                               __hip_bfloat16* __restrict__ B2) {
    const float* W = blockIdx.z ? W2f : W1f;
    __hip_bfloat16* BT = blockIdx.z ? B2 : B1;
    __shared__ float tile[32][33];
    const int bk = blockIdx.x * 32, bn = blockIdx.y * 32;
    const int tx = threadIdx.x & 31, ty = threadIdx.x >> 5;  // ty 0..7
#pragma unroll
    for (int i = 0; i < 32; i += 8)
        tile[ty + i][tx] = W[(size_t)(bk + ty + i) * DIM + bn + tx];
    __syncthreads();
#pragma unroll
    for (int i = 0; i < 32; i += 8)
        BT[(size_t)(bn + ty + i) * DIM + bk + tx] = __float2bfloat16(tile[tx][ty + i]);
}

// ---------------- bf16 MFMA GEMM + fused alpha epilogue ----------------
// C[M,512] = A[M,512] @ B (B given as BT[n][k]).
// TILE 64x128 (was 128x128): grid (4, 313) = 1252 blocks -> ~20 waves/CU (2x the old 628
// blocks) -- the 2-barrier K-loop was occupancy-starved (R2: dbuf alone didn't move it).
// 4 waves; wave w owns the full 64 rows x 32-col slab [wc, wc+32), 4x2 of 16x16x32 MFMA.
// GRID: col-slab on FAST axis -> the 4 blocks sharing an A row-tile dispatch consecutively
// and A re-reads hit L2. K-loop: 2-phase double-buffered LDS, stage(k+32) issued before
// compute(k). C-store staged through LDS -> coalesced bf16x8 stores.
// Alpha epilogue: wave's 32-col partial dot -> atomicAdd into zero-init'd p_as/p_ad.
//   H=8: p_as[row*8 + head], head = 2*bx + (wave>>1) (two waves share a head).
//   H=1: p_as[row] directly (full 512-col dot accumulates across all slabs) -> sum8_k gone.

template <int H>
__global__ __launch_bounds__(256) void gemm_mfma(const short* __restrict__ A,
                                                 const short* __restrict__ BT,
                                                 __hip_bfloat16* __restrict__ C,
                                                 const float* __restrict__ a_s,
                                                 const float* __restrict__ a_d,
                                                 float* __restrict__ p_as,
                                                 float* __restrict__ p_ad,
                                                 int M) {
    // As = 64x32 (2048), Bs = 128x32 (4096); double buffered = 12288 shorts (24 KB).
    // Epilogue reuses [0, 64*136) for the C staging tile.
    __shared__ __align__(16) short SMEM[12288];
    short* As0 = SMEM;
    short* Bs0 = SMEM + 2048;
    short* As1 = SMEM + 6144;
    short* Bs1 = SMEM + 8192;
    const int t = threadIdx.x;
    const int rowBase = blockIdx.y * 64;    // row-tile on the SLOW axis
    const int colBase = blockIdx.x * 128;   // col-slab on the FAST axis (A L2 reuse)
    const int wave = t >> 6, lane = t & 63;
    const int wc = wave * 32;               // wave's 32-col slab within the 128-col tile
    const int quad = lane >> 4, l16 = lane & 15;

    f32x4 acc[4][2];
#pragma unroll
    for (int i = 0; i < 4; i++)
#pragma unroll
        for (int j = 0; j < 2; j++) acc[i][j] = f32x4{0.f, 0.f, 0.f, 0.f};

    const int srow = t >> 2;                // 0..63
    const int skof = (t & 3) * 8;
    int ar = rowBase + srow;  if (ar > M - 1) ar = M - 1;
    const int bn0 = colBase + srow;
    const int bn1 = colBase + 64 + srow;

    auto stage = [&](int k0, short* As, short* Bs) {
        gload_lds16(A + (size_t)ar * DIM + k0 + skof, As + t * 8);
        gload_lds16(BT + (size_t)bn0 * DIM + k0 + skof, Bs + t * 8);
        gload_lds16(BT + (size_t)bn1 * DIM + k0 + skof, Bs + 2048 + t * 8);
    };
    auto compute = [&](const short* As, const short* Bs) {
        bf16x8 af[4], bfr[2];
#pragma unroll
        for (int i = 0; i < 4; i++)
            af[i] = *(const bf16x8*)&As[(i * 16 + l16) * 32 + quad * 8];
#pragma unroll
        for (int j = 0; j < 2; j++)
            bfr[j] = *(const bf16x8*)&Bs[(wc + j * 16 + l16) * 32 + quad * 8];
#pragma unroll
        for (int i = 0; i < 4; i++)
#pragma unroll
            for (int j = 0; j < 2; j++)
                acc[i][j] = __builtin_amdgcn_mfma_f32_16x16x32_bf16(af[i], bfr[j], acc[i][j], 0, 0, 0);
    };

    stage(0, As0, Bs0);
    __syncthreads();
    for (int k0 = 0; k0 < DIM; k0 += 64) {
        if (k0 + 32 < DIM) stage(k0 + 32, As1, Bs1);  // prefetch next half-step
        compute(As0, Bs0);
        __syncthreads();                              // drains vmcnt -> buf1 ready
        if (k0 + 64 < DIM) stage(k0 + 64, As0, Bs0);
        compute(As1, Bs1);
        __syncthreads();
    }

    // ---- C store via LDS staging (single pass; waves own disjoint 32-col slabs)
#pragma unroll
    for (int i = 0; i < 4; i++)
#pragma unroll
        for (int j = 0; j < 2; j++)
#pragma unroll
            for (int r = 0; r < 4; r++)
                SMEM[(i * 16 + quad * 4 + r) * 136 + wc + j * 16 + l16] = f2bf(acc[i][j][r]);
    __syncthreads();
#pragma unroll
    for (int k = 0; k < 4; k++) {
        const int row = k * 16 + (t >> 4);
        const int col = (t & 15) * 8;
        const int gr = rowBase + row;
        if (gr < M) {
            bf16x8 vv = *(const bf16x8*)&SMEM[row * 136 + col];
            *(bf16x8*)&C[(size_t)gr * DIM + colBase + col] = vv;
        }
    }

    // ---- alpha epilogue: partial dot of the wave's 32-col slab, atomicAdd-combined.
    // Coefficient index == global column for both H=8 ([8][64] flat) and H=1 ([512]).
    const int head = (H == 8) ? (2 * blockIdx.x + (wave >> 1)) : 0;
    float asc[2], adc[2];
#pragma unroll
    for (int j = 0; j < 2; j++) {
        asc[j] = a_s[colBase + wc + j * 16 + l16];
        adc[j] = a_d[colBase + wc + j * 16 + l16];
    }
#pragma unroll
    for (int i = 0; i < 4; i++) {
#pragma unroll
        for (int r = 0; r < 4; r++) {
            float vs = acc[i][0][r] * asc[0] + acc[i][1][r] * asc[1];
            float vd = acc[i][0][r] * adc[0] + acc[i][1][r] * adc[1];
#pragma unroll
            for (int o = 8; o; o >>= 1) { vs += __shfl_down(vs, o); vd += __shfl_down(vd, o); }
            if (l16 == 0) {
                const int row = rowBase + i * 16 + quad * 4 + r;
                if (row < M) {
                    atomicAdd(&p_as[(size_t)row * H + head], vs);
                    atomicAdd(&p_ad[(size_t)row * H + head], vd);
                }
            }
        }
    }
}

// ---------------- fused aggregation: ONE WAVE PER NODE (h in bf16) ----------------
// EXACT R0 structure (340.9 us measured): batch-4 main loop, serial tail, 64-wide sort,
// plain loads/stores. R2/R4 proved agg is at its L2-fill-traffic floor (~234 MB at
// ~3.8 TB/s fabric BW): deeper ILP (-occupancy), nt stores, and fp16 fma_mix all lost time.
// x_res/x_out may alias (same-thread RAW) -> no __restrict__.

template <int H>
__global__ __launch_bounds__(256) void agg_k(const __hip_bfloat16* __restrict__ h,
                                             const float* __restrict__ alp_s,
                                             const float* __restrict__ alp_d,
                                             const int* __restrict__ off,
                                             const int* __restrict__ slot,
                                             const float* __restrict__ bias,
                                             const float* __restrict__ gamma,
                                             const float* __restrict__ beta,
                                             const float* x_res,
                                             float* x_out,
                                             __hip_bfloat16* x_out_b) {
    const int wid = threadIdx.x >> 6;
    const int lane = threadIdx.x & 63;
    const int n = blockIdx.x * 4 + wid;
    const int head = (H == 8) ? (lane >> 3) : 0;

    const int o0 = off[n];
    const int deg = off[n + 1] - o0;
    const int total = deg + 1;  // + self loop (virtual edge -> src = n)

    const float ad = (H == 8) ? alp_d[(size_t)n * 8 + head] : alp_d[n];

    // coalesced load of src list (+ self loop) into lanes, then 64-lane bitonic sort ascending
    int v = 0x7fffffff;
    if (lane < total && lane < 64) v = (lane < deg) ? slot[o0 + lane] : n;
#pragma unroll
    for (int k = 2; k <= 64; k <<= 1) {
#pragma unroll
        for (int j = k >> 1; j > 0; j >>= 1) {
            int o = __shfl_xor(v, j);
            bool takeMin = (((lane & k) == 0) == ((lane & j) == 0));
            v = takeMin ? min(v, o) : max(v, o);
        }
    }
    const int nsort = (total < 64) ? total : 64;

    float acc[8];
#pragma unroll
    for (int r = 0; r < 8; r++) acc[r] = 0.f;
    float ld = 0.f;
    const unsigned short* hu = (const unsigned short*)h;

    auto zcomp = [&](int s) -> float {
        float z = ((H == 8) ? alp_s[(size_t)s * 8 + head] : alp_s[s]) + ad;
        return (z >= 0.f) ? z : NEG_SLOPE * z;
    };
    auto fmarow = [&](const u32x4& rv, float p) {
#pragma unroll
        for (int q = 0; q < 4; q++) {
            unsigned int u = rv[q];
            acc[2 * q]     += p * __uint_as_float(u << 16);
            acc[2 * q + 1] += p * __uint_as_float(u & 0xffff0000u);
        }
    };

    int e = 0;
    for (; e + 4 <= nsort; e += 4) {
        const int s0 = __shfl(v, e), s1 = __shfl(v, e + 1);
        const int s2 = __shfl(v, e + 2), s3 = __shfl(v, e + 3);
        // issue all 4 row loads + 4 alpha loads before consuming
        const u32x4 r0 = *(const u32x4*)(hu + (size_t)s0 * DIM + lane * 8);
        const u32x4 r1 = *(const u32x4*)(hu + (size_t)s1 * DIM + lane * 8);
        const u32x4 r2 = *(const u32x4*)(hu + (size_t)s2 * DIM + lane * 8);
        const u32x4 r3 = *(const u32x4*)(hu + (size_t)s3 * DIM + lane * 8);
        const float z0 = zcomp(s0), z1 = zcomp(s1), z2 = zcomp(s2), z3 = zcomp(s3);
        const float p0 = __expf(z0), p1 = __expf(z1), p2 = __expf(z2), p3 = __expf(z3);
        ld += p0; fmarow(r0, p0);
        ld += p1; fmarow(r1, p1);
        ld += p2; fmarow(r2, p2);
        ld += p3; fmarow(r3, p3);
    }
    for (; e < nsort; e++) {
        const int s = __shfl(v, e);
        const u32x4 rv = *(const u32x4*)(hu + (size_t)s * DIM + lane * 8);
        const float p = __expf(zcomp(s));
        ld += p; fmarow(rv, p);
    }
    // rare tail: degree+1 > 64 (unsorted; includes self loop when deg >= 64)
    for (int e2 = 64; e2 < total; e2++) {
        const int s = (e2 < deg) ? slot[o0 + e2] : n;
        const u32x4 rv = *(const u32x4*)(hu + (size_t)s * DIM + lane * 8);
        const float p = __expf(zcomp(s));
        ld += p; fmarow(rv, p);
    }

    // normalize + bias (ld is already the full per-head denominator)
    const float inv = 1.f / ld;
    const int c0 = lane * 8;
    const float4 ba = *(const float4*)&bias[c0];
    const float4 bb = *(const float4*)&bias[c0 + 4];
    float xn[8];
    xn[0] = acc[0] * inv + ba.x; xn[1] = acc[1] * inv + ba.y;
    xn[2] = acc[2] * inv + ba.z; xn[3] = acc[3] * inv + ba.w;
    xn[4] = acc[4] * inv + bb.x; xn[5] = acc[5] * inv + bb.y;
    xn[6] = acc[6] * inv + bb.z; xn[7] = acc[7] * inv + bb.w;

    // LayerNorm stats: in-wave butterfly over 64 lanes
    float s1 = 0.f, s2 = 0.f;
#pragma unroll
    for (int r = 0; r < 8; r++) { s1 += xn[r]; s2 += xn[r] * xn[r]; }
#pragma unroll
    for (int o = 32; o; o >>= 1) { s1 += __shfl_xor(s1, o); s2 += __shfl_xor(s2, o); }
    const float mu = s1 * (1.f / DIM);
    const float rs = rsqrtf(s2 * (1.f / DIM) - mu * mu + LN_EPS);

    const float4 ga = *(const float4*)&gamma[c0];
    const float4 gb = *(const float4*)&gamma[c0 + 4];
    const float4 ea = *(const float4*)&beta[c0];
    const float4 eb = *(const float4*)&beta[c0 + 4];
    const float4 xa = *(const float4*)&x_res[(size_t)n * DIM + c0];
    const float4 xb = *(const float4*)&x_res[(size_t)n * DIM + c0 + 4];
    const float gv[8] = {ga.x, ga.y, ga.z, ga.w, gb.x, gb.y, gb.z, gb.w};
    const float ev[8] = {ea.x, ea.y, ea.z, ea.w, eb.x, eb.y, eb.z, eb.w};
    const float xv[8] = {xa.x, xa.y, xa.z, xa.w, xb.x, xb.y, xb.z, xb.w};

    float out[8];
#pragma unroll
    for (int r = 0; r < 8; r++) {
        float y = (xn[r] - mu) * rs * gv[r] + ev[r];
        y = (y > 0.f) ? y : expm1f(y);
        out[r] = xv[r] + y;
    }
    *(float4*)&x_out[(size_t)n * DIM + c0]     = make_float4(out[0], out[1], out[2], out[3]);
    *(float4*)&x_out[(size_t)n * DIM + c0 + 4] = make_float4(out[4], out[5], out[6], out[7]);
    if (x_out_b) {  // fused fp32->bf16 for next layer's GEMM input
        __hip_bfloat16 tb[8];
#pragma unroll
        for (int r = 0; r < 8; r++) tb[r] = __float2bfloat16(out[r]);
        *(bf16x8*)&x_out_b[(size_t)n * DIM + c0] = *(bf16x8*)tb;
    }
}

// ---------------- launch ----------------

extern "C" void kernel_launch(void* const* d_in, const int* in_sizes, int n_in,
                              void* d_out, int out_size, void* d_ws, size_t ws_size,
                              hipStream_t stream) {
    const float* x = (const float*)d_in[0];
    const int* ei = (const int*)d_in[1];   // int inputs arrive as int32
    const float* W1 = (const float*)d_in[2];
    const float* as1 = (const float*)d_in[3];
    const float* ad1 = (const float*)d_in[4];
    const float* b1 = (const float*)d_in[5];
    const float* g1 = (const float*)d_in[6];
    const float* be1 = (const float*)d_in[7];
    const float* W2 = (const float*)d_in[8];
    const float* as2 = (const float*)d_in[9];
    const float* ad2 = (const float*)d_in[10];
    const float* b2 = (const float*)d_in[11];
    const float* g2 = (const float*)d_in[12];
    const float* be2 = (const float*)d_in[13];
    float* out = (float*)d_out;

    char* ws = (char*)d_ws;
    size_t o = 0;
    auto alloc = [&](size_t bytes) { size_t r = o; o += (bytes + 255) & ~(size_t)255; return r; };
    int* p_cnt = (int*)(ws + alloc((size_t)NN * 4));
    int* p_off = (int*)(ws + alloc((size_t)(NN + 1) * 4));
    int* p_cur = (int*)(ws + alloc((size_t)NN * 4));
    int* p_slot = (int*)(ws + alloc((size_t)NE * 4));
    __hip_bfloat16* p_hb = (__hip_bfloat16*)(ws + alloc((size_t)NN * DIM * 2));  // h (bf16)
    __hip_bfloat16* p_xb = (__hip_bfloat16*)(ws + alloc((size_t)NN * DIM * 2));  // GEMM A input (bf16)
    __hip_bfloat16* p_bt1 = (__hip_bfloat16*)(ws + alloc((size_t)DIM * DIM * 2));
    __hip_bfloat16* p_bt2 = (__hip_bfloat16*)(ws + alloc((size_t)DIM * DIM * 2));
    float* p_as = (float*)(ws + alloc((size_t)NN * 8 * 4));    // H=8: [NN][8]; H=1: [NN] (atomic)
    float* p_ad = (float*)(ws + alloc((size_t)NN * 8 * 4));
    float* p_x1 = out;  // layer-1 output lives in d_out (overwritten by layer 2)

    const int* e_src = ei;
    const int* e_dst = ei + NE;

    hipMemsetAsync(p_cnt, 0, (size_t)NN * 4, stream);
    count_k<<<(NE + 255) / 256, 256, 0, stream>>>(e_dst, p_cnt);
    scan_k<<<1, 1024, 0, stream>>>(p_cnt, p_off, p_cur);
    fill_k<<<(NE + 255) / 256, 256, 0, stream>>>(e_src, e_dst, p_cur, p_slot);

    const int NX = NN * DIM;  // 10.24M
    dim3 ggrid(4, (NN + 63) / 64);   // 64-row tiles; col-slab on the FAST axis

    convT_k<<<dim3(16, 16, 2), 256, 0, stream>>>(W1, W2, p_bt1, p_bt2);
    conv_k<<<(NX / 4 + 255) / 256, 256, 0, stream>>>(x, p_xb, NX);

    // ---- layer 1 (H=8): alpha accumulated via atomicAdd into zeroed buffers
    hipMemsetAsync(p_as, 0, (size_t)NN * 8 * 4, stream);
    hipMemsetAsync(p_ad, 0, (size_t)NN * 8 * 4, stream);
    gemm_mfma<8><<<ggrid, 256, 0, stream>>>((const short*)p_xb, (const short*)p_bt1, p_hb,
                                            as1, ad1, p_as, p_ad, NN);
    agg_k<8><<<NN / 4, 256, 0, stream>>>(p_hb, p_as, p_ad, p_off, p_slot, b1, g1, be1,
                                         x, p_x1, p_xb);

    // ---- layer 2 (H=1): alpha accumulated directly into flat [NN] (sum8_k eliminated)
    hipMemsetAsync(p_as, 0, (size_t)NN * 4, stream);
    hipMemsetAsync(p_ad, 0, (size_t)NN * 4, stream);
    gemm_mfma<1><<<ggrid, 256, 0, stream>>>((const short*)p_xb, (const short*)p_bt2, p_hb,
                                            as2, ad2, p_as, p_ad, NN);
    agg_k<1><<<NN / 4, 256, 0, stream>>>(p_hb, p_as, p_ad, p_off, p_slot, b2, g2, be2,
                                         p_x1, out, nullptr);
}

// Round 6
// 352.286 us; speedup vs baseline: 1.0785x; 1.0785x over previous
//
#include <hip/hip_runtime.h>
#include <hip/hip_bf16.h>
#include <math.h>

#define NN 20000
#define NE 320000
#define DIM 512
#define LN_EPS 1e-5f
#define NEG_SLOPE 0.2f

typedef __attribute__((ext_vector_type(8))) short bf16x8;
typedef __attribute__((ext_vector_type(4))) float f32x4;
typedef __attribute__((ext_vector_type(4))) unsigned int u32x4;

__device__ inline void gload_lds16(const void* g, void* l) {
    __builtin_amdgcn_global_load_lds(
        (const __attribute__((address_space(1))) void*)g,
        (__attribute__((address_space(3))) void*)l, 16, 0, 0);
}

__device__ inline short f2bf(float f) {
    __hip_bfloat16 b = __float2bfloat16(f);
    return *reinterpret_cast<short*>(&b);
}

// ---------------- CSR build (edge_index arrives as int32: [src(E), dst(E)]) ----------------

__global__ void count_k(const int* __restrict__ dst, int* __restrict__ cnt) {
    int e = blockIdx.x * blockDim.x + threadIdx.x;
    if (e < NE) {
        int d = dst[e];
        d = (d < 0) ? 0 : (d >= NN ? NN - 1 : d);
        atomicAdd(&cnt[d], 1);
    }
}

__global__ __launch_bounds__(1024) void scan_k(const int* __restrict__ cnt,
                                               int* __restrict__ off,
                                               int* __restrict__ cur) {
    __shared__ int s[1024];
    const int t = threadIdx.x;
    const int lo = t * 20;
    int loc[20];
    int sum = 0;
#pragma unroll
    for (int i = 0; i < 20; i++) {
        int idx = lo + i;
        int v = (idx < NN) ? cnt[idx] : 0;
        loc[i] = v; sum += v;
    }
    s[t] = sum;
    __syncthreads();
    for (int o = 1; o < 1024; o <<= 1) {
        int x = (t >= o) ? s[t - o] : 0;
        __syncthreads();
        s[t] += x;
        __syncthreads();
    }
    int run = s[t] - sum;  // exclusive prefix
#pragma unroll
    for (int i = 0; i < 20; i++) {
        int idx = lo + i;
        if (idx < NN) { off[idx] = run; cur[idx] = run; run += loc[i]; }
    }
    if (t == 1023) off[NN] = s[1023];
}

__global__ void fill_k(const int* __restrict__ src, const int* __restrict__ dst,
                       int* __restrict__ cur, int* __restrict__ slot) {
    int e = blockIdx.x * blockDim.x + threadIdx.x;
    if (e < NE) {
        int d = dst[e];
        d = (d < 0) ? 0 : (d >= NN ? NN - 1 : d);
        int sv = src[e];
        sv = (sv < 0) ? 0 : (sv >= NN ? NN - 1 : sv);
        int p = atomicAdd(&cur[d], 1);
        slot[p] = sv;
    }
}

// ---------------- converts ----------------

__global__ void conv_k(const float* __restrict__ in, __hip_bfloat16* __restrict__ out, int n) {
    int i = (blockIdx.x * blockDim.x + threadIdx.x) * 4;
    if (i < n) {
        float4 v = *(const float4*)&in[i];
        out[i + 0] = __float2bfloat16(v.x);
        out[i + 1] = __float2bfloat16(v.y);
        out[i + 2] = __float2bfloat16(v.z);
        out[i + 3] = __float2bfloat16(v.w);
    }
}

// W[512][512] fp32 -> BT[n][k] bf16 (transpose); z selects (W1->B1, W2->B2)
__global__ __launch_bounds__(256) void convT_k(const float* __restrict__ W1f,
                                               const float* __restrict__ W2f,
                                               __hip_bfloat16* __restrict__ B1,
                                               __hip_bfloat16* __restrict__ B2) {
    const float* W = blockIdx.z ? W2f : W1f;
    __hip_bfloat16* BT = blockIdx.z ? B2 : B1;
    __shared__ float tile[32][33];
    const int bk = blockIdx.x * 32, bn = blockIdx.y * 32;
    const int tx = threadIdx.x & 31, ty = threadIdx.x >> 5;  // ty 0..7
#pragma unroll
    for (int i = 0; i < 32; i += 8)
        tile[ty + i][tx] = W[(size_t)(bk + ty + i) * DIM + bn + tx];
    __syncthreads();
#pragma unroll
    for (int i = 0; i < 32; i += 8)
        BT[(size_t)(bn + ty + i) * DIM + bk + tx] = __float2bfloat16(tile[tx][ty + i]);
}

// collapse 8 column-block alpha partials [8][NN] -> flat [NN] (H=1 layer)
__global__ void sum8_k(const float* __restrict__ ps, const float* __restrict__ pd,
                       float* __restrict__ os, float* __restrict__ od) {
    int n = blockIdx.x * blockDim.x + threadIdx.x;
    if (n < NN) {
        float a = 0.f, b = 0.f;
#pragma unroll
        for (int k = 0; k < 8; k++) { a += ps[(size_t)k * NN + n]; b += pd[(size_t)k * NN + n]; }
        os[n] = a; od[n] = b;
    }
}

// ---------------- bf16 MFMA GEMM + fused alpha epilogue ----------------
// C[M,512] = A[M,512] @ B (B given as BT[n][k]). 128x128 tile, 4 waves, 4x4 of 16x16x32 MFMA.
// GRID: (4, 157), col-slab on the FAST axis -> A-tile L2 reuse (R0-proven geometry).
// K-loop: BK=64 (8 steps of {stage, barrier, 32 MFMA, barrier} instead of 16 of 16-MFMA
// steps): halves the full-drain barrier count and amortizes each stage latency over 2x
// the MFMA work. LDS [128][64] rows are 128B -> XOR-swizzled (T2 / rule #21 pattern):
// gload_lds dest stays LINEAR; the global SOURCE column is permuted col8 = (s&7)^(row&7);
// the ds_read address XORs (row&7)<<3 shorts. Involution verified; read conflicts ~2-way.
// Single-buffer 32KB (dbuf measured neutral in R2; preserves occupancy).
// C-store staged through LDS -> coalesced bf16x8 stores (R0 epilogue, unchanged).
// H=8: wave's 64-col slab == head (2*bx + (wave&1)); H=1: [8][NN] partials -> sum8_k.

template <int H>
__global__ __launch_bounds__(256) void gemm_mfma(const short* __restrict__ A,
                                                 const short* __restrict__ BT,
                                                 __hip_bfloat16* __restrict__ C,
                                                 const float* __restrict__ a_s,
                                                 const float* __restrict__ a_d,
                                                 float* __restrict__ p_as,
                                                 float* __restrict__ p_ad,
                                                 int M) {
    __shared__ __align__(16) short SMEM[16384];  // As[128][64]=8192 + Bs[128][64]=8192 (32 KB)
    short* As = SMEM;
    short* Bs = SMEM + 8192;
    const int t = threadIdx.x;
    const int rowBase = blockIdx.y * 128;   // row-tile on the SLOW axis
    const int colBase = blockIdx.x * 128;   // col-slab on the FAST axis (A L2 reuse)
    const int wave = t >> 6, lane = t & 63;
    const int wr = (wave >> 1) * 64;
    const int wc = (wave & 1) * 64;
    const int quad = lane >> 4, l16 = lane & 15;

    f32x4 acc[4][4];
#pragma unroll
    for (int i = 0; i < 4; i++)
#pragma unroll
        for (int j = 0; j < 4; j++) acc[i][j] = f32x4{0.f, 0.f, 0.f, 0.f};

    // stage: 1024 16B-slots per operand; thread t handles slots s = t + 256*i (i=0..3).
    // LDS dest short-offset = 8*s (linear, lane-contiguous per wave -> gload_lds legal).
    // Logical element stored there: row = s>>3, col8 = 8*((s&7) ^ (row&7))  [pre-swizzle].
    auto stage = [&](int k0) {
#pragma unroll
        for (int i = 0; i < 4; i++) {
            const int s = t + 256 * i;
            const int row = s >> 3;
            const int col = 8 * ((s & 7) ^ (row & 7));
            int arow = rowBase + row; if (arow > M - 1) arow = M - 1;
            gload_lds16(A + (size_t)arow * DIM + k0 + col, As + 8 * s);
            const int brow = colBase + row;   // BT row == output column
            gload_lds16(BT + (size_t)brow * DIM + k0 + col, Bs + 8 * s);
        }
    };
    // read back with the matching XOR: shorts offset = row*64 + ((kk*32 + quad*8) ^ ((row&7)<<3))
    auto compute = [&](int kk) {
        bf16x8 af[4], bfr[4];
#pragma unroll
        for (int i = 0; i < 4; i++) {
            const int row = wr + i * 16 + l16;
            af[i] = *(const bf16x8*)&As[row * 64 + ((kk * 32 + quad * 8) ^ ((row & 7) << 3))];
        }
#pragma unroll
        for (int j = 0; j < 4; j++) {
            const int row = wc + j * 16 + l16;
            bfr[j] = *(const bf16x8*)&Bs[row * 64 + ((kk * 32 + quad * 8) ^ ((row & 7) << 3))];
        }
#pragma unroll
        for (int i = 0; i < 4; i++)
#pragma unroll
            for (int j = 0; j < 4; j++)
                acc[i][j] = __builtin_amdgcn_mfma_f32_16x16x32_bf16(af[i], bfr[j], acc[i][j], 0, 0, 0);
    };

    for (int k0 = 0; k0 < DIM; k0 += 64) {
        stage(k0);
        __syncthreads();      // drains vmcnt -> buffer ready
        compute(0);
        compute(1);
        __syncthreads();      // all reads done before next overwrite
    }

    // ---- C store via LDS staging: pass p covers rows [64p, 64p+64)
#pragma unroll
    for (int p = 0; p < 2; p++) {
        if ((wave >> 1) == p) {
#pragma unroll
            for (int i = 0; i < 4; i++)
#pragma unroll
                for (int j = 0; j < 4; j++)
#pragma unroll
                    for (int r = 0; r < 4; r++)
                        SMEM[(i * 16 + quad * 4 + r) * 136 + wc + j * 16 + l16] =
                            f2bf(acc[i][j][r]);
        }
        __syncthreads();
#pragma unroll
        for (int k = 0; k < 4; k++) {
            const int row = k * 16 + (t >> 4);
            const int col = (t & 15) * 8;
            const int gr = rowBase + p * 64 + row;
            if (gr < M) {
                bf16x8 vv = *(const bf16x8*)&SMEM[row * 136 + col];
                *(bf16x8*)&C[(size_t)gr * DIM + colBase + col] = vv;
            }
        }
        __syncthreads();
    }

    // ---- alpha epilogue: dot of this wave's 64-col slab with a_s/a_d coefficients
    const int slab = 2 * blockIdx.x + (wave & 1);               // head id (H=8) / partial slot (H=1)
    const int cb = (H == 8) ? slab * 64 : (colBase + wc);       // coefficient base (equal values)
    float asc[4], adc[4];
#pragma unroll
    for (int j = 0; j < 4; j++) {
        asc[j] = a_s[cb + j * 16 + l16];
        adc[j] = a_d[cb + j * 16 + l16];
    }
#pragma unroll
    for (int i = 0; i < 4; i++) {
#pragma unroll
        for (int r = 0; r < 4; r++) {
            float vs = acc[i][0][r] * asc[0] + acc[i][1][r] * asc[1] +
                       acc[i][2][r] * asc[2] + acc[i][3][r] * asc[3];
            float vd = acc[i][0][r] * adc[0] + acc[i][1][r] * adc[1] +
                       acc[i][2][r] * adc[2] + acc[i][3][r] * adc[3];
#pragma unroll
            for (int o = 8; o; o >>= 1) { vs += __shfl_down(vs, o); vd += __shfl_down(vd, o); }
            if (l16 == 0) {
                const int row = rowBase + wr + i * 16 + quad * 4 + r;
                if (row < M) {
                    if (H == 8) {
                        p_as[(size_t)row * 8 + slab] = vs;
                        p_ad[(size_t)row * 8 + slab] = vd;
                    } else {
                        p_as[(size_t)slab * NN + row] = vs;
                        p_ad[(size_t)slab * NN + row] = vd;
                    }
                }
            }
        }
    }
}

// ---------------- fused aggregation: ONE WAVE PER NODE (h in bf16) ----------------
// EXACT R0 structure (340.9 us measured; reproduced at 61.5 us/dispatch in R5): batch-4
// main loop, serial tail, 64-wide sort, plain loads/stores. R2/R4 proved agg sits at its
// L2-miss-traffic floor (~234 MB at ~3.9 TB/s): deeper ILP, nt stores, and fp16 fma_mix
// all lost time. DO NOT TOUCH.
// x_res/x_out may alias (same-thread RAW) -> no __restrict__.

template <int H>
__global__ __launch_bounds__(256) void agg_k(const __hip_bfloat16* __restrict__ h,
                                             const float* __restrict__ alp_s,
                                             const float* __restrict__ alp_d,
                                             const int* __restrict__ off,
                                             const int* __restrict__ slot,
                                             const float* __restrict__ bias,
                                             const float* __restrict__ gamma,
                                             const float* __restrict__ beta,
                                             const float* x_res,
                                             float* x_out,
                                             __hip_bfloat16* x_out_b) {
    const int wid = threadIdx.x >> 6;
    const int lane = threadIdx.x & 63;
    const int n = blockIdx.x * 4 + wid;
    const int head = (H == 8) ? (lane >> 3) : 0;

    const int o0 = off[n];
    const int deg = off[n + 1] - o0;
    const int total = deg + 1;  // + self loop (virtual edge -> src = n)

    const float ad = (H == 8) ? alp_d[(size_t)n * 8 + head] : alp_d[n];

    // coalesced load of src list (+ self loop) into lanes, then 64-lane bitonic sort ascending
    int v = 0x7fffffff;
    if (lane < total && lane < 64) v = (lane < deg) ? slot[o0 + lane] : n;
#pragma unroll
    for (int k = 2; k <= 64; k <<= 1) {
#pragma unroll
        for (int j = k >> 1; j > 0; j >>= 1) {
            int o = __shfl_xor(v, j);
            bool takeMin = (((lane & k) == 0) == ((lane & j) == 0));
            v = takeMin ? min(v, o) : max(v, o);
        }
    }
    const int nsort = (total < 64) ? total : 64;

    float acc[8];
#pragma unroll
    for (int r = 0; r < 8; r++) acc[r] = 0.f;
    float ld = 0.f;
    const unsigned short* hu = (const unsigned short*)h;

    auto zcomp = [&](int s) -> float {
        float z = ((H == 8) ? alp_s[(size_t)s * 8 + head] : alp_s[s]) + ad;
        return (z >= 0.f) ? z : NEG_SLOPE * z;
    };
    auto fmarow = [&](const u32x4& rv, float p) {
#pragma unroll
        for (int q = 0; q < 4; q++) {
            unsigned int u = rv[q];
            acc[2 * q]     += p * __uint_as_float(u << 16);
            acc[2 * q + 1] += p * __uint_as_float(u & 0xffff0000u);
        }
    };

    int e = 0;
    for (; e + 4 <= nsort; e += 4) {
        const int s0 = __shfl(v, e), s1 = __shfl(v, e + 1);
        const int s2 = __shfl(v, e + 2), s3 = __shfl(v, e + 3);
        // issue all 4 row loads + 4 alpha loads before consuming
        const u32x4 r0 = *(const u32x4*)(hu + (size_t)s0 * DIM + lane * 8);
        const u32x4 r1 = *(const u32x4*)(hu + (size_t)s1 * DIM + lane * 8);
        const u32x4 r2 = *(const u32x4*)(hu + (size_t)s2 * DIM + lane * 8);
        const u32x4 r3 = *(const u32x4*)(hu + (size_t)s3 * DIM + lane * 8);
        const float z0 = zcomp(s0), z1 = zcomp(s1), z2 = zcomp(s2), z3 = zcomp(s3);
        const float p0 = __expf(z0), p1 = __expf(z1), p2 = __expf(z2), p3 = __expf(z3);
        ld += p0; fmarow(r0, p0);
        ld += p1; fmarow(r1, p1);
        ld += p2; fmarow(r2, p2);
        ld += p3; fmarow(r3, p3);
    }
    for (; e < nsort; e++) {
        const int s = __shfl(v, e);
        const u32x4 rv = *(const u32x4*)(hu + (size_t)s * DIM + lane * 8);
        const float p = __expf(zcomp(s));
        ld += p; fmarow(rv, p);
    }
    // rare tail: degree+1 > 64 (unsorted; includes self loop when deg >= 64)
    for (int e2 = 64; e2 < total; e2++) {
        const int s = (e2 < deg) ? slot[o0 + e2] : n;
        const u32x4 rv = *(const u32x4*)(hu + (size_t)s * DIM + lane * 8);
        const float p = __expf(zcomp(s));
        ld += p; fmarow(rv, p);
    }

    // normalize + bias (ld is already the full per-head denominator)
    const float inv = 1.f / ld;
    const int c0 = lane * 8;
    const float4 ba = *(const float4*)&bias[c0];
    const float4 bb = *(const float4*)&bias[c0 + 4];
    float xn[8];
    xn[0] = acc[0] * inv + ba.x; xn[1] = acc[1] * inv + ba.y;
    xn[2] = acc[2] * inv + ba.z; xn[3] = acc[3] * inv + ba.w;
    xn[4] = acc[4] * inv + bb.x; xn[5] = acc[5] * inv + bb.y;
    xn[6] = acc[6] * inv + bb.z; xn[7] = acc[7] * inv + bb.w;

    // LayerNorm stats: in-wave butterfly over 64 lanes
    float s1 = 0.f, s2 = 0.f;
#pragma unroll
    for (int r = 0; r < 8; r++) { s1 += xn[r]; s2 += xn[r] * xn[r]; }
#pragma unroll
    for (int o = 32; o; o >>= 1) { s1 += __shfl_xor(s1, o); s2 += __shfl_xor(s2, o); }
    const float mu = s1 * (1.f / DIM);
    const float rs = rsqrtf(s2 * (1.f / DIM) - mu * mu + LN_EPS);

    const float4 ga = *(const float4*)&gamma[c0];
    const float4 gb = *(const float4*)&gamma[c0 + 4];
    const float4 ea = *(const float4*)&beta[c0];
    const float4 eb = *(const float4*)&beta[c0 + 4];
    const float4 xa = *(const float4*)&x_res[(size_t)n * DIM + c0];
    const float4 xb = *(const float4*)&x_res[(size_t)n * DIM + c0 + 4];
    const float gv[8] = {ga.x, ga.y, ga.z, ga.w, gb.x, gb.y, gb.z, gb.w};
    const float ev[8] = {ea.x, ea.y, ea.z, ea.w, eb.x, eb.y, eb.z, eb.w};
    const float xv[8] = {xa.x, xa.y, xa.z, xa.w, xb.x, xb.y, xb.z, xb.w};

    float out[8];
#pragma unroll
    for (int r = 0; r < 8; r++) {
        float y = (xn[r] - mu) * rs * gv[r] + ev[r];
        y = (y > 0.f) ? y : expm1f(y);
        out[r] = xv[r] + y;
    }
    *(float4*)&x_out[(size_t)n * DIM + c0]     = make_float4(out[0], out[1], out[2], out[3]);
    *(float4*)&x_out[(size_t)n * DIM + c0 + 4] = make_float4(out[4], out[5], out[6], out[7]);
    if (x_out_b) {  // fused fp32->bf16 for next layer's GEMM input
        __hip_bfloat16 tb[8];
#pragma unroll
        for (int r = 0; r < 8; r++) tb[r] = __float2bfloat16(out[r]);
        *(bf16x8*)&x_out_b[(size_t)n * DIM + c0] = *(bf16x8*)tb;
    }
}

// ---------------- launch ----------------

extern "C" void kernel_launch(void* const* d_in, const int* in_sizes, int n_in,
                              void* d_out, int out_size, void* d_ws, size_t ws_size,
                              hipStream_t stream) {
    const float* x = (const float*)d_in[0];
    const int* ei = (const int*)d_in[1];   // int inputs arrive as int32
    const float* W1 = (const float*)d_in[2];
    const float* as1 = (const float*)d_in[3];
    const float* ad1 = (const float*)d_in[4];
    const float* b1 = (const float*)d_in[5];
    const float* g1 = (const float*)d_in[6];
    const float* be1 = (const float*)d_in[7];
    const float* W2 = (const float*)d_in[8];
    const float* as2 = (const float*)d_in[9];
    const float* ad2 = (const float*)d_in[10];
    const float* b2 = (const float*)d_in[11];
    const float* g2 = (const float*)d_in[12];
    const float* be2 = (const float*)d_in[13];
    float* out = (float*)d_out;

    char* ws = (char*)d_ws;
    size_t o = 0;
    auto alloc = [&](size_t bytes) { size_t r = o; o += (bytes + 255) & ~(size_t)255; return r; };
    int* p_cnt = (int*)(ws + alloc((size_t)NN * 4));
    int* p_off = (int*)(ws + alloc((size_t)(NN + 1) * 4));
    int* p_cur = (int*)(ws + alloc((size_t)NN * 4));
    int* p_slot = (int*)(ws + alloc((size_t)NE * 4));
    __hip_bfloat16* p_hb = (__hip_bfloat16*)(ws + alloc((size_t)NN * DIM * 2));  // h (bf16)
    __hip_bfloat16* p_xb = (__hip_bfloat16*)(ws + alloc((size_t)NN * DIM * 2));  // GEMM A input (bf16)
    __hip_bfloat16* p_bt1 = (__hip_bfloat16*)(ws + alloc((size_t)DIM * DIM * 2));
    __hip_bfloat16* p_bt2 = (__hip_bfloat16*)(ws + alloc((size_t)DIM * DIM * 2));
    float* p_as = (float*)(ws + alloc((size_t)NN * 8 * 4));    // H=8: [NN][8]; H=1: [8][NN] partials
    float* p_ad = (float*)(ws + alloc((size_t)NN * 8 * 4));
    float* p_as2 = (float*)(ws + alloc((size_t)NN * 4));       // H=1: summed alpha_s
    float* p_ad2 = (float*)(ws + alloc((size_t)NN * 4));       // H=1: summed alpha_d
    float* p_x1 = out;  // layer-1 output lives in d_out (overwritten by layer 2)

    const int* e_src = ei;
    const int* e_dst = ei + NE;

    hipMemsetAsync(p_cnt, 0, (size_t)NN * 4, stream);
    count_k<<<(NE + 255) / 256, 256, 0, stream>>>(e_dst, p_cnt);
    scan_k<<<1, 1024, 0, stream>>>(p_cnt, p_off, p_cur);
    fill_k<<<(NE + 255) / 256, 256, 0, stream>>>(e_src, e_dst, p_cur, p_slot);

    const int NX = NN * DIM;  // 10.24M
    dim3 ggrid(4, (NN + 127) / 128);   // col-slab FAST axis -> A-tile L2 reuse

    convT_k<<<dim3(16, 16, 2), 256, 0, stream>>>(W1, W2, p_bt1, p_bt2);
    conv_k<<<(NX / 4 + 255) / 256, 256, 0, stream>>>(x, p_xb, NX);

    // ---- layer 1 (H=8)
    gemm_mfma<8><<<ggrid, 256, 0, stream>>>((const short*)p_xb, (const short*)p_bt1, p_hb,
                                            as1, ad1, p_as, p_ad, NN);
    agg_k<8><<<NN / 4, 256, 0, stream>>>(p_hb, p_as, p_ad, p_off, p_slot, b1, g1, be1,
                                         x, p_x1, p_xb);

    // ---- layer 2 (H=1; alpha written as 8 slab partials, then collapsed)
    gemm_mfma<1><<<ggrid, 256, 0, stream>>>((const short*)p_xb, (const short*)p_bt2, p_hb,
                                            as2, ad2, p_as, p_ad, NN);
    sum8_k<<<(NN + 255) / 256, 256, 0, stream>>>(p_as, p_ad, p_as2, p_ad2);
    agg_k<1><<<NN / 4, 256, 0, stream>>>(p_hb, p_as2, p_ad2, p_off, p_slot, b2, g2, be2,
                                         p_x1, out, nullptr);
}

// Round 7
// 327.957 us; speedup vs baseline: 1.1585x; 1.0742x over previous
//
#include <hip/hip_runtime.h>
#include <hip/hip_bf16.h>
#include <math.h>

#define NN 20000
#define NE 320000
#define DIM 512
#define LN_EPS 1e-5f
#define NEG_SLOPE 0.2f

typedef __attribute__((ext_vector_type(8))) short bf16x8;
typedef __attribute__((ext_vector_type(4))) float f32x4;
typedef __attribute__((ext_vector_type(4))) unsigned int u32x4;

__device__ inline void gload_lds16(const void* g, void* l) {
    __builtin_amdgcn_global_load_lds(
        (const __attribute__((address_space(1))) void*)g,
        (__attribute__((address_space(3))) void*)l, 16, 0, 0);
}

__device__ inline short f2bf(float f) {
    __hip_bfloat16 b = __float2bfloat16(f);
    return *reinterpret_cast<short*>(&b);
}

__device__ inline float bf2f(short u) {
    return __uint_as_float(((unsigned int)(unsigned short)u) << 16);
}

// ---------------- CSR build (edge_index arrives as int32: [src(E), dst(E)]) ----------------

__global__ void count_k(const int* __restrict__ dst, int* __restrict__ cnt) {
    int e = blockIdx.x * blockDim.x + threadIdx.x;
    if (e < NE) {
        int d = dst[e];
        d = (d < 0) ? 0 : (d >= NN ? NN - 1 : d);
        atomicAdd(&cnt[d], 1);
    }
}

__global__ __launch_bounds__(1024) void scan_k(const int* __restrict__ cnt,
                                               int* __restrict__ off,
                                               int* __restrict__ cur) {
    __shared__ int s[1024];
    const int t = threadIdx.x;
    const int lo = t * 20;
    int loc[20];
    int sum = 0;
#pragma unroll
    for (int i = 0; i < 20; i++) {
        int idx = lo + i;
        int v = (idx < NN) ? cnt[idx] : 0;
        loc[i] = v; sum += v;
    }
    s[t] = sum;
    __syncthreads();
    for (int o = 1; o < 1024; o <<= 1) {
        int x = (t >= o) ? s[t - o] : 0;
        __syncthreads();
        s[t] += x;
        __syncthreads();
    }
    int run = s[t] - sum;  // exclusive prefix
#pragma unroll
    for (int i = 0; i < 20; i++) {
        int idx = lo + i;
        if (idx < NN) { off[idx] = run; cur[idx] = run; run += loc[i]; }
    }
    if (t == 1023) off[NN] = s[1023];
}

__global__ void fill_k(const int* __restrict__ src, const int* __restrict__ dst,
                       int* __restrict__ cur, int* __restrict__ slot) {
    int e = blockIdx.x * blockDim.x + threadIdx.x;
    if (e < NE) {
        int d = dst[e];
        d = (d < 0) ? 0 : (d >= NN ? NN - 1 : d);
        int sv = src[e];
        sv = (sv < 0) ? 0 : (sv >= NN ? NN - 1 : sv);
        int p = atomicAdd(&cur[d], 1);
        slot[p] = sv;
    }
}

// ---------------- converts ----------------

// conv (x fp32 -> bf16) + fused p_cnt zeroing (replaces the hipMemsetAsync dispatch).
// Blocks [0, NB_CONV) convert; blocks [NB_CONV, NB_CONV+20) zero 5000 int4s of cnt.
#define NB_CONV 10000
__global__ void convz_k(const float* __restrict__ in, __hip_bfloat16* __restrict__ out,
                        int* __restrict__ cnt) {
    if (blockIdx.x < NB_CONV) {
        int i = (blockIdx.x * blockDim.x + threadIdx.x) * 4;
        float4 v = *(const float4*)&in[i];
        out[i + 0] = __float2bfloat16(v.x);
        out[i + 1] = __float2bfloat16(v.y);
        out[i + 2] = __float2bfloat16(v.z);
        out[i + 3] = __float2bfloat16(v.w);
    } else {
        int idx = (blockIdx.x - NB_CONV) * 256 + threadIdx.x;
        if (idx < NN / 4) ((int4*)cnt)[idx] = make_int4(0, 0, 0, 0);
    }
}

// W[512][512] fp32 -> BT[n][k] bf16 (transpose); z selects (W1->B1, W2->B2)
__global__ __launch_bounds__(256) void convT_k(const float* __restrict__ W1f,
                                               const float* __restrict__ W2f,
                                               __hip_bfloat16* __restrict__ B1,
                                               __hip_bfloat16* __restrict__ B2) {
    const float* W = blockIdx.z ? W2f : W1f;
    __hip_bfloat16* BT = blockIdx.z ? B2 : B1;
    __shared__ float tile[32][33];
    const int bk = blockIdx.x * 32, bn = blockIdx.y * 32;
    const int tx = threadIdx.x & 31, ty = threadIdx.x >> 5;  // ty 0..7
#pragma unroll
    for (int i = 0; i < 32; i += 8)
        tile[ty + i][tx] = W[(size_t)(bk + ty + i) * DIM + bn + tx];
    __syncthreads();
#pragma unroll
    for (int i = 0; i < 32; i += 8)
        BT[(size_t)(bn + ty + i) * DIM + bk + tx] = __float2bfloat16(tile[tx][ty + i]);
}

// collapse 8 column-block alpha partials [8][NN] -> flat [NN] (H=1 layer)
__global__ void sum8_k(const float* __restrict__ ps, const float* __restrict__ pd,
                       float* __restrict__ os, float* __restrict__ od) {
    int n = blockIdx.x * blockDim.x + threadIdx.x;
    if (n < NN) {
        float a = 0.f, b = 0.f;
#pragma unroll
        for (int k = 0; k < 8; k++) { a += ps[(size_t)k * NN + n]; b += pd[(size_t)k * NN + n]; }
        os[n] = a; od[n] = b;
    }
}

// ---------------- bf16 MFMA GEMM + fused alpha epilogue (EXACT R0 config) ----------------
// C[M,512] = A[M,512] @ B (B given as BT[n][k]). 128x128 tile, 4 waves, 4x4 of 16x16x32 MFMA.
// GRID: (4, 157) with col-slab on the FAST axis -> A-tile L2 reuse.
// R2 (pipelined dbuf): neutral. R5 (64x128+atomics): -40us. R6 (BK=64+swizzle): -13us.
// R0's 16-step single-buffer loop is the measured local optimum -- keep it.

template <int H>
__global__ __launch_bounds__(256) void gemm_mfma(const short* __restrict__ A,
                                                 const short* __restrict__ BT,
                                                 __hip_bfloat16* __restrict__ C,
                                                 const float* __restrict__ a_s,
                                                 const float* __restrict__ a_d,
                                                 float* __restrict__ p_as,
                                                 float* __restrict__ p_ad,
                                                 int M) {
    __shared__ __align__(16) short SMEM[64 * 136];  // staging: As=4096, Bs=4096; epilogue: 64x136
    short* As = SMEM;
    short* Bs = SMEM + 4096;
    const int t = threadIdx.x;
    const int rowBase = blockIdx.y * 128;   // row-tile on the SLOW axis
    const int colBase = blockIdx.x * 128;   // col-slab on the FAST axis (A L2 reuse)
    const int wave = t >> 6, lane = t & 63;
    const int wr = (wave >> 1) * 64;
    const int wc = (wave & 1) * 64;
    const int quad = lane >> 4, l16 = lane & 15;

    f32x4 acc[4][4];
#pragma unroll
    for (int i = 0; i < 4; i++)
#pragma unroll
        for (int j = 0; j < 4; j++) acc[i][j] = f32x4{0.f, 0.f, 0.f, 0.f};

    const int srow = t >> 2;
    const int skof = (t & 3) * 8;
    int ar0 = rowBase + srow;       if (ar0 > M - 1) ar0 = M - 1;
    int ar1 = rowBase + 64 + srow;  if (ar1 > M - 1) ar1 = M - 1;
    const int bn0 = colBase + srow;
    const int bn1 = colBase + 64 + srow;

    for (int k0 = 0; k0 < DIM; k0 += 32) {
        gload_lds16(A + (size_t)ar0 * DIM + k0 + skof, As + t * 8);
        gload_lds16(A + (size_t)ar1 * DIM + k0 + skof, As + 2048 + t * 8);
        gload_lds16(BT + (size_t)bn0 * DIM + k0 + skof, Bs + t * 8);
        gload_lds16(BT + (size_t)bn1 * DIM + k0 + skof, Bs + 2048 + t * 8);
        __syncthreads();

        bf16x8 af[4], bfr[4];
#pragma unroll
        for (int i = 0; i < 4; i++)
            af[i] = *(const bf16x8*)&As[(wr + i * 16 + l16) * 32 + quad * 8];
#pragma unroll
        for (int j = 0; j < 4; j++)
            bfr[j] = *(const bf16x8*)&Bs[(wc + j * 16 + l16) * 32 + quad * 8];
#pragma unroll
        for (int i = 0; i < 4; i++)
#pragma unroll
            for (int j = 0; j < 4; j++)
                acc[i][j] = __builtin_amdgcn_mfma_f32_16x16x32_bf16(af[i], bfr[j], acc[i][j], 0, 0, 0);
        __syncthreads();
    }

    // ---- C store via LDS staging: pass p covers rows [64p, 64p+64)
#pragma unroll
    for (int p = 0; p < 2; p++) {
        if ((wave >> 1) == p) {
#pragma unroll
            for (int i = 0; i < 4; i++)
#pragma unroll
                for (int j = 0; j < 4; j++)
#pragma unroll
                    for (int r = 0; r < 4; r++)
                        SMEM[(i * 16 + quad * 4 + r) * 136 + wc + j * 16 + l16] =
                            f2bf(acc[i][j][r]);
        }
        __syncthreads();
#pragma unroll
        for (int k = 0; k < 4; k++) {
            const int row = k * 16 + (t >> 4);
            const int col = (t & 15) * 8;
            const int gr = rowBase + p * 64 + row;
            if (gr < M) {
                bf16x8 vv = *(const bf16x8*)&SMEM[row * 136 + col];
                *(bf16x8*)&C[(size_t)gr * DIM + colBase + col] = vv;
            }
        }
        __syncthreads();
    }

    // ---- alpha epilogue: dot of this wave's 64-col slab with a_s/a_d coefficients
    const int slab = 2 * blockIdx.x + (wave & 1);               // head id (H=8) / partial slot (H=1)
    const int cb = (H == 8) ? slab * 64 : (colBase + wc);       // coefficient base (equal values)
    float asc[4], adc[4];
#pragma unroll
    for (int j = 0; j < 4; j++) {
        asc[j] = a_s[cb + j * 16 + l16];
        adc[j] = a_d[cb + j * 16 + l16];
    }
#pragma unroll
    for (int i = 0; i < 4; i++) {
#pragma unroll
        for (int r = 0; r < 4; r++) {
            float vs = acc[i][0][r] * asc[0] + acc[i][1][r] * asc[1] +
                       acc[i][2][r] * asc[2] + acc[i][3][r] * asc[3];
            float vd = acc[i][0][r] * adc[0] + acc[i][1][r] * adc[1] +
                       acc[i][2][r] * adc[2] + acc[i][3][r] * adc[3];
#pragma unroll
            for (int o = 8; o; o >>= 1) { vs += __shfl_down(vs, o); vd += __shfl_down(vd, o); }
            if (l16 == 0) {
                const int row = rowBase + wr + i * 16 + quad * 4 + r;
                if (row < M) {
                    if (H == 8) {
                        p_as[(size_t)row * 8 + slab] = vs;
                        p_ad[(size_t)row * 8 + slab] = vd;
                    } else {
                        p_as[(size_t)slab * NN + row] = vs;
                        p_ad[(size_t)slab * NN + row] = vd;
                    }
                }
            }
        }
    }
}

// ---------------- fused aggregation: ONE WAVE PER NODE (h in bf16) ----------------
// Main loop = EXACT R0 structure (reproduced at 61.4-61.6 us x4 rounds: L2-fill floor).
// EPILOGUE CHANGE (traffic only): the residual is read as bf16 from p_xb (which already
// holds bf16(x) / bf16(x1) for the GEMM), and the L1 fp32 x_out write is DROPPED -- L2's
// residual is the bf16 copy. Cuts 82 MB/iter of L2-fill traffic at the measured floor.
// x_resb/x_out_b alias in L1 (same-thread same-row RAW) -> no __restrict__ on those.

template <int H>
__global__ __launch_bounds__(256) void agg_k(const __hip_bfloat16* __restrict__ h,
                                             const float* __restrict__ alp_s,
                                             const float* __restrict__ alp_d,
                                             const int* __restrict__ off,
                                             const int* __restrict__ slot,
                                             const float* __restrict__ bias,
                                             const float* __restrict__ gamma,
                                             const float* __restrict__ beta,
                                             const __hip_bfloat16* x_resb,
                                             float* x_out,
                                             __hip_bfloat16* x_out_b) {
    const int wid = threadIdx.x >> 6;
    const int lane = threadIdx.x & 63;
    const int n = blockIdx.x * 4 + wid;
    const int head = (H == 8) ? (lane >> 3) : 0;

    const int o0 = off[n];
    const int deg = off[n + 1] - o0;
    const int total = deg + 1;  // + self loop (virtual edge -> src = n)

    const float ad = (H == 8) ? alp_d[(size_t)n * 8 + head] : alp_d[n];

    // coalesced load of src list (+ self loop) into lanes, then 64-lane bitonic sort ascending
    int v = 0x7fffffff;
    if (lane < total && lane < 64) v = (lane < deg) ? slot[o0 + lane] : n;
#pragma unroll
    for (int k = 2; k <= 64; k <<= 1) {
#pragma unroll
        for (int j = k >> 1; j > 0; j >>= 1) {
            int o = __shfl_xor(v, j);
            bool takeMin = (((lane & k) == 0) == ((lane & j) == 0));
            v = takeMin ? min(v, o) : max(v, o);
        }
    }
    const int nsort = (total < 64) ? total : 64;

    float acc[8];
#pragma unroll
    for (int r = 0; r < 8; r++) acc[r] = 0.f;
    float ld = 0.f;
    const unsigned short* hu = (const unsigned short*)h;

    auto zcomp = [&](int s) -> float {
        float z = ((H == 8) ? alp_s[(size_t)s * 8 + head] : alp_s[s]) + ad;
        return (z >= 0.f) ? z : NEG_SLOPE * z;
    };
    auto fmarow = [&](const u32x4& rv, float p) {
#pragma unroll
        for (int q = 0; q < 4; q++) {
            unsigned int u = rv[q];
            acc[2 * q]     += p * __uint_as_float(u << 16);
            acc[2 * q + 1] += p * __uint_as_float(u & 0xffff0000u);
        }
    };

    int e = 0;
    for (; e + 4 <= nsort; e += 4) {
        const int s0 = __shfl(v, e), s1 = __shfl(v, e + 1);
        const int s2 = __shfl(v, e + 2), s3 = __shfl(v, e + 3);
        // issue all 4 row loads + 4 alpha loads before consuming
        const u32x4 r0 = *(const u32x4*)(hu + (size_t)s0 * DIM + lane * 8);
        const u32x4 r1 = *(const u32x4*)(hu + (size_t)s1 * DIM + lane * 8);
        const u32x4 r2 = *(const u32x4*)(hu + (size_t)s2 * DIM + lane * 8);
        const u32x4 r3 = *(const u32x4*)(hu + (size_t)s3 * DIM + lane * 8);
        const float z0 = zcomp(s0), z1 = zcomp(s1), z2 = zcomp(s2), z3 = zcomp(s3);
        const float p0 = __expf(z0), p1 = __expf(z1), p2 = __expf(z2), p3 = __expf(z3);
        ld += p0; fmarow(r0, p0);
        ld += p1; fmarow(r1, p1);
        ld += p2; fmarow(r2, p2);
        ld += p3; fmarow(r3, p3);
    }
    for (; e < nsort; e++) {
        const int s = __shfl(v, e);
        const u32x4 rv = *(const u32x4*)(hu + (size_t)s * DIM + lane * 8);
        const float p = __expf(zcomp(s));
        ld += p; fmarow(rv, p);
    }
    // rare tail: degree+1 > 64 (unsorted; includes self loop when deg >= 64)
    for (int e2 = 64; e2 < total; e2++) {
        const int s = (e2 < deg) ? slot[o0 + e2] : n;
        const u32x4 rv = *(const u32x4*)(hu + (size_t)s * DIM + lane * 8);
        const float p = __expf(zcomp(s));
        ld += p; fmarow(rv, p);
    }

    // normalize + bias (ld is already the full per-head denominator)
    const float inv = 1.f / ld;
    const int c0 = lane * 8;
    const float4 ba = *(const float4*)&bias[c0];
    const float4 bb = *(const float4*)&bias[c0 + 4];
    float xn[8];
    xn[0] = acc[0] * inv + ba.x; xn[1] = acc[1] * inv + ba.y;
    xn[2] = acc[2] * inv + ba.z; xn[3] = acc[3] * inv + ba.w;
    xn[4] = acc[4] * inv + bb.x; xn[5] = acc[5] * inv + bb.y;
    xn[6] = acc[6] * inv + bb.z; xn[7] = acc[7] * inv + bb.w;

    // LayerNorm stats: in-wave butterfly over 64 lanes
    float s1 = 0.f, s2 = 0.f;
#pragma unroll
    for (int r = 0; r < 8; r++) { s1 += xn[r]; s2 += xn[r] * xn[r]; }
#pragma unroll
    for (int o = 32; o; o >>= 1) { s1 += __shfl_xor(s1, o); s2 += __shfl_xor(s2, o); }
    const float mu = s1 * (1.f / DIM);
    const float rs = rsqrtf(s2 * (1.f / DIM) - mu * mu + LN_EPS);

    const float4 ga = *(const float4*)&gamma[c0];
    const float4 gb = *(const float4*)&gamma[c0 + 4];
    const float4 ea = *(const float4*)&beta[c0];
    const float4 eb = *(const float4*)&beta[c0 + 4];
    const bf16x8 xrv = *(const bf16x8*)&x_resb[(size_t)n * DIM + c0];
    const float gv[8] = {ga.x, ga.y, ga.z, ga.w, gb.x, gb.y, gb.z, gb.w};
    const float ev[8] = {ea.x, ea.y, ea.z, ea.w, eb.x, eb.y, eb.z, eb.w};

    float out[8];
#pragma unroll
    for (int r = 0; r < 8; r++) {
        float y = (xn[r] - mu) * rs * gv[r] + ev[r];
        y = (y > 0.f) ? y : expm1f(y);
        out[r] = bf2f(xrv[r]) + y;
    }
    if (x_out) {
        *(float4*)&x_out[(size_t)n * DIM + c0]     = make_float4(out[0], out[1], out[2], out[3]);
        *(float4*)&x_out[(size_t)n * DIM + c0 + 4] = make_float4(out[4], out[5], out[6], out[7]);
    }
    if (x_out_b) {  // fused fp32->bf16 for next layer's GEMM input + residual
        __hip_bfloat16 tb[8];
#pragma unroll
        for (int r = 0; r < 8; r++) tb[r] = __float2bfloat16(out[r]);
        *(bf16x8*)&x_out_b[(size_t)n * DIM + c0] = *(bf16x8*)tb;
    }
}

// ---------------- launch ----------------

extern "C" void kernel_launch(void* const* d_in, const int* in_sizes, int n_in,
                              void* d_out, int out_size, void* d_ws, size_t ws_size,
                              hipStream_t stream) {
    const float* x = (const float*)d_in[0];
    const int* ei = (const int*)d_in[1];   // int inputs arrive as int32
    const float* W1 = (const float*)d_in[2];
    const float* as1 = (const float*)d_in[3];
    const float* ad1 = (const float*)d_in[4];
    const float* b1 = (const float*)d_in[5];
    const float* g1 = (const float*)d_in[6];
    const float* be1 = (const float*)d_in[7];
    const float* W2 = (const float*)d_in[8];
    const float* as2 = (const float*)d_in[9];
    const float* ad2 = (const float*)d_in[10];
    const float* b2 = (const float*)d_in[11];
    const float* g2 = (const float*)d_in[12];
    const float* be2 = (const float*)d_in[13];
    float* out = (float*)d_out;

    char* ws = (char*)d_ws;
    size_t o = 0;
    auto alloc = [&](size_t bytes) { size_t r = o; o += (bytes + 255) & ~(size_t)255; return r; };
    int* p_cnt = (int*)(ws + alloc((size_t)NN * 4));
    int* p_off = (int*)(ws + alloc((size_t)(NN + 1) * 4));
    int* p_cur = (int*)(ws + alloc((size_t)NN * 4));
    int* p_slot = (int*)(ws + alloc((size_t)NE * 4));
    __hip_bfloat16* p_hb = (__hip_bfloat16*)(ws + alloc((size_t)NN * DIM * 2));  // h (bf16)
    __hip_bfloat16* p_xb = (__hip_bfloat16*)(ws + alloc((size_t)NN * DIM * 2));  // bf16 x / x1 (GEMM A + residual)
    __hip_bfloat16* p_bt1 = (__hip_bfloat16*)(ws + alloc((size_t)DIM * DIM * 2));
    __hip_bfloat16* p_bt2 = (__hip_bfloat16*)(ws + alloc((size_t)DIM * DIM * 2));
    float* p_as = (float*)(ws + alloc((size_t)NN * 8 * 4));    // H=8: [NN][8]; H=1: [8][NN] partials
    float* p_ad = (float*)(ws + alloc((size_t)NN * 8 * 4));
    float* p_as2 = (float*)(ws + alloc((size_t)NN * 4));       // H=1: summed alpha_s
    float* p_ad2 = (float*)(ws + alloc((size_t)NN * 4));       // H=1: summed alpha_d

    const int* e_src = ei;
    const int* e_dst = ei + NE;

    // conv + p_cnt zeroing fused (memset dispatch eliminated); runs before count_k.
    convz_k<<<NB_CONV + 20, 256, 0, stream>>>(x, p_xb, p_cnt);
    count_k<<<(NE + 255) / 256, 256, 0, stream>>>(e_dst, p_cnt);
    scan_k<<<1, 1024, 0, stream>>>(p_cnt, p_off, p_cur);
    fill_k<<<(NE + 255) / 256, 256, 0, stream>>>(e_src, e_dst, p_cur, p_slot);

    dim3 ggrid(4, (NN + 127) / 128);   // col-slab FAST axis -> A-tile L2 reuse

    convT_k<<<dim3(16, 16, 2), 256, 0, stream>>>(W1, W2, p_bt1, p_bt2);

    // ---- layer 1 (H=8): residual read from bf16 p_xb; output written ONLY as bf16 into p_xb
    gemm_mfma<8><<<ggrid, 256, 0, stream>>>((const short*)p_xb, (const short*)p_bt1, p_hb,
                                            as1, ad1, p_as, p_ad, NN);
    agg_k<8><<<NN / 4, 256, 0, stream>>>(p_hb, p_as, p_ad, p_off, p_slot, b1, g1, be1,
                                         p_xb, nullptr, p_xb);

    // ---- layer 2 (H=1): residual read from bf16 p_xb (= bf16(x1)); final out in fp32
    gemm_mfma<1><<<ggrid, 256, 0, stream>>>((const short*)p_xb, (const short*)p_bt2, p_hb,
                                            as2, ad2, p_as, p_ad, NN);
    sum8_k<<<(NN + 255) / 256, 256, 0, stream>>>(p_as, p_ad, p_as2, p_ad2);
    agg_k<1><<<NN / 4, 256, 0, stream>>>(p_hb, p_as2, p_ad2, p_off, p_slot, b2, g2, be2,
                                         p_xb, out, nullptr);
}

// Round 8
// 310.674 us; speedup vs baseline: 1.2230x; 1.0556x over previous
//
#include <hip/hip_runtime.h>
#include <hip/hip_bf16.h>
#include <math.h>

#define NN 20000
#define NE 320000
#define DIM 512
#define LN_EPS 1e-5f
#define NEG_SLOPE 0.2f

typedef __attribute__((ext_vector_type(8))) short bf16x8;
typedef __attribute__((ext_vector_type(4))) float f32x4;
typedef __attribute__((ext_vector_type(4))) unsigned int u32x4;

__device__ inline void gload_lds16(const void* g, void* l) {
    __builtin_amdgcn_global_load_lds(
        (const __attribute__((address_space(1))) void*)g,
        (__attribute__((address_space(3))) void*)l, 16, 0, 0);
}

__device__ inline short f2bf(float f) {
    __hip_bfloat16 b = __float2bfloat16(f);
    return *reinterpret_cast<short*>(&b);
}

__device__ inline float bf2f(short u) {
    return __uint_as_float(((unsigned int)(unsigned short)u) << 16);
}

// ---------------- CSR build pieces (count is fused into gemm8's tail blocks) ----------------

__global__ __launch_bounds__(1024) void scan_k(const int* __restrict__ cnt,
                                               int* __restrict__ off,
                                               int* __restrict__ cur) {
    __shared__ int s[1024];
    const int t = threadIdx.x;
    const int lo = t * 20;
    int loc[20];
    int sum = 0;
#pragma unroll
    for (int i = 0; i < 20; i++) {
        int idx = lo + i;
        int v = (idx < NN) ? cnt[idx] : 0;
        loc[i] = v; sum += v;
    }
    s[t] = sum;
    __syncthreads();
    for (int o = 1; o < 1024; o <<= 1) {
        int x = (t >= o) ? s[t - o] : 0;
        __syncthreads();
        s[t] += x;
        __syncthreads();
    }
    int run = s[t] - sum;  // exclusive prefix
#pragma unroll
    for (int i = 0; i < 20; i++) {
        int idx = lo + i;
        if (idx < NN) { off[idx] = run; cur[idx] = run; run += loc[i]; }
    }
    if (t == 1023) off[NN] = s[1023];
}

__global__ void fill_k(const int* __restrict__ src, const int* __restrict__ dst,
                       int* __restrict__ cur, int* __restrict__ slot) {
    int e = blockIdx.x * blockDim.x + threadIdx.x;
    if (e < NE) {
        int d = dst[e];
        d = (d < 0) ? 0 : (d >= NN ? NN - 1 : d);
        int sv = src[e];
        sv = (sv < 0) ? 0 : (sv >= NN ? NN - 1 : sv);
        int p = atomicAdd(&cur[d], 1);
        slot[p] = sv;
    }
}

// ---------------- fused pre-pass: conv x->bf16 | zero cnt | transpose W1,W2 -> bf16 ----------------
// Flat grid: [0, NB_CONV) conv; [NB_CONV, NB_CONV+NB_ZERO) zero cnt; rest = 512 convT blocks.
#define NB_CONV 10000
#define NB_ZERO 20
__global__ __launch_bounds__(256) void convz_k(const float* __restrict__ in,
                                               __hip_bfloat16* __restrict__ out,
                                               int* __restrict__ cnt,
                                               const float* __restrict__ W1f,
                                               const float* __restrict__ W2f,
                                               __hip_bfloat16* __restrict__ B1,
                                               __hip_bfloat16* __restrict__ B2) {
    const int b = blockIdx.x;
    if (b < NB_CONV) {
        int i = (b * 256 + threadIdx.x) * 4;
        float4 v = *(const float4*)&in[i];
        out[i + 0] = __float2bfloat16(v.x);
        out[i + 1] = __float2bfloat16(v.y);
        out[i + 2] = __float2bfloat16(v.z);
        out[i + 3] = __float2bfloat16(v.w);
    } else if (b < NB_CONV + NB_ZERO) {
        int idx = (b - NB_CONV) * 256 + threadIdx.x;
        if (idx < NN / 4) ((int4*)cnt)[idx] = make_int4(0, 0, 0, 0);
    } else {
        // W[512][512] fp32 -> BT[n][k] bf16 (transpose); idx>>8 selects W1/W2
        const int idx = b - (NB_CONV + NB_ZERO);       // 0..511
        const int z = idx >> 8;
        const int rem = idx & 255;
        const int bk = (rem & 15) * 32, bn = (rem >> 4) * 32;
        const float* W = z ? W2f : W1f;
        __hip_bfloat16* BT = z ? B2 : B1;
        __shared__ float tile[32][33];
        const int tx = threadIdx.x & 31, ty = threadIdx.x >> 5;  // ty 0..7
#pragma unroll
        for (int i = 0; i < 32; i += 8)
            tile[ty + i][tx] = W[(size_t)(bk + ty + i) * DIM + bn + tx];
        __syncthreads();
#pragma unroll
        for (int i = 0; i < 32; i += 8)
            BT[(size_t)(bn + ty + i) * DIM + bk + tx] = __float2bfloat16(tile[tx][ty + i]);
    }
}

// ---------------- bf16 MFMA GEMM + fused alpha epilogue (R0 K-loop, unchanged) ----------------
// C[M,512] = A[M,512] @ B (B given as BT[n][k]). 128x128 tile, 4 waves, 4x4 of 16x16x32 MFMA.
// Flat 1D grid, b = blockIdx.x: b < gemmBlocks -> gemm block (bx = b&3 col-slab FAST -> A L2
// reuse, by = b>>2); b >= gemmBlocks -> count_k tail block (H=8 launch only; cnt was zeroed
// by convz_k one dispatch earlier; block-uniform early return, touches no LDS/barrier).
// H=8: wave's 64-col slab == head (2*bx + (wave&1)); alpha -> p_as[row*8+head] direct store.
// H=1: wave's 64-col partial dot -> atomicAdd into flat p_as[row]/p_ad[row] (zeroed by agg8)
//      -- replaces the old [8][NN] partials + sum8_k dispatch.

template <int H>
__global__ __launch_bounds__(256) void gemm_mfma(const short* __restrict__ A,
                                                 const short* __restrict__ BT,
                                                 __hip_bfloat16* __restrict__ C,
                                                 const float* __restrict__ a_s,
                                                 const float* __restrict__ a_d,
                                                 float* __restrict__ p_as,
                                                 float* __restrict__ p_ad,
                                                 int M,
                                                 const int* __restrict__ e_dst,
                                                 int* __restrict__ cnt,
                                                 int gemmBlocks) {
    const int b = blockIdx.x;
    if (b >= gemmBlocks) {  // fused count_k tail (H=8 launch)
        int e = (b - gemmBlocks) * 256 + threadIdx.x;
        if (e < NE) {
            int d = e_dst[e];
            d = (d < 0) ? 0 : (d >= NN ? NN - 1 : d);
            atomicAdd(&cnt[d], 1);
        }
        return;
    }
    __shared__ __align__(16) short SMEM[64 * 136];  // staging: As=4096, Bs=4096; epilogue: 64x136
    short* As = SMEM;
    short* Bs = SMEM + 4096;
    const int t = threadIdx.x;
    const int rowBase = (b >> 2) * 128;     // row-tile on the SLOW axis
    const int colBase = (b & 3) * 128;      // col-slab on the FAST axis (A L2 reuse)
    const int wave = t >> 6, lane = t & 63;
    const int wr = (wave >> 1) * 64;
    const int wc = (wave & 1) * 64;
    const int quad = lane >> 4, l16 = lane & 15;

    f32x4 acc[4][4];
#pragma unroll
    for (int i = 0; i < 4; i++)
#pragma unroll
        for (int j = 0; j < 4; j++) acc[i][j] = f32x4{0.f, 0.f, 0.f, 0.f};

    const int srow = t >> 2;
    const int skof = (t & 3) * 8;
    int ar0 = rowBase + srow;       if (ar0 > M - 1) ar0 = M - 1;
    int ar1 = rowBase + 64 + srow;  if (ar1 > M - 1) ar1 = M - 1;
    const int bn0 = colBase + srow;
    const int bn1 = colBase + 64 + srow;

    for (int k0 = 0; k0 < DIM; k0 += 32) {
        gload_lds16(A + (size_t)ar0 * DIM + k0 + skof, As + t * 8);
        gload_lds16(A + (size_t)ar1 * DIM + k0 + skof, As + 2048 + t * 8);
        gload_lds16(BT + (size_t)bn0 * DIM + k0 + skof, Bs + t * 8);
        gload_lds16(BT + (size_t)bn1 * DIM + k0 + skof, Bs + 2048 + t * 8);
        __syncthreads();

        bf16x8 af[4], bfr[4];
#pragma unroll
        for (int i = 0; i < 4; i++)
            af[i] = *(const bf16x8*)&As[(wr + i * 16 + l16) * 32 + quad * 8];
#pragma unroll
        for (int j = 0; j < 4; j++)
            bfr[j] = *(const bf16x8*)&Bs[(wc + j * 16 + l16) * 32 + quad * 8];
#pragma unroll
        for (int i = 0; i < 4; i++)
#pragma unroll
            for (int j = 0; j < 4; j++)
                acc[i][j] = __builtin_amdgcn_mfma_f32_16x16x32_bf16(af[i], bfr[j], acc[i][j], 0, 0, 0);
        __syncthreads();
    }

    // ---- C store via LDS staging: pass p covers rows [64p, 64p+64)
#pragma unroll
    for (int p = 0; p < 2; p++) {
        if ((wave >> 1) == p) {
#pragma unroll
            for (int i = 0; i < 4; i++)
#pragma unroll
                for (int j = 0; j < 4; j++)
#pragma unroll
                    for (int r = 0; r < 4; r++)
                        SMEM[(i * 16 + quad * 4 + r) * 136 + wc + j * 16 + l16] =
                            f2bf(acc[i][j][r]);
        }
        __syncthreads();
#pragma unroll
        for (int k = 0; k < 4; k++) {
            const int row = k * 16 + (t >> 4);
            const int col = (t & 15) * 8;
            const int gr = rowBase + p * 64 + row;
            if (gr < M) {
                bf16x8 vv = *(const bf16x8*)&SMEM[row * 136 + col];
                *(bf16x8*)&C[(size_t)gr * DIM + colBase + col] = vv;
            }
        }
        __syncthreads();
    }

    // ---- alpha epilogue: dot of this wave's 64-col slab with a_s/a_d coefficients
    const int slab = 2 * (b & 3) + (wave & 1);                  // head id (H=8)
    const int cb = (H == 8) ? slab * 64 : (colBase + wc);       // coefficient base (equal values)
    float asc[4], adc[4];
#pragma unroll
    for (int j = 0; j < 4; j++) {
        asc[j] = a_s[cb + j * 16 + l16];
        adc[j] = a_d[cb + j * 16 + l16];
    }
#pragma unroll
    for (int i = 0; i < 4; i++) {
#pragma unroll
        for (int r = 0; r < 4; r++) {
            float vs = acc[i][0][r] * asc[0] + acc[i][1][r] * asc[1] +
                       acc[i][2][r] * asc[2] + acc[i][3][r] * asc[3];
            float vd = acc[i][0][r] * adc[0] + acc[i][1][r] * adc[1] +
                       acc[i][2][r] * adc[2] + acc[i][3][r] * adc[3];
#pragma unroll
            for (int o = 8; o; o >>= 1) { vs += __shfl_down(vs, o); vd += __shfl_down(vd, o); }
            if (l16 == 0) {
                const int row = rowBase + wr + i * 16 + quad * 4 + r;
                if (row < M) {
                    if (H == 8) {
                        p_as[(size_t)row * 8 + slab] = vs;
                        p_ad[(size_t)row * 8 + slab] = vd;
                    } else {
                        atomicAdd(&p_as[row], vs);
                        atomicAdd(&p_ad[row], vd);
                    }
                }
            }
        }
    }
}

// ---------------- fused aggregation: ONE WAVE PER NODE (h in bf16) ----------------
// Main loop = EXACT R0 structure (5 rounds reproduced at its L2-miss-traffic floor).
// R7 epilogue: residual read as bf16 from p_xb; L1 writes ONLY bf16 (into p_xb).
// H=8 extra (R8): 4 threads/block zero p_as2/p_ad2 for gemm1's atomic alpha epilogue
// (agg8 completes before gemm1 launches -> ordering safe). DO NOT TOUCH the edge loop.

template <int H>
__global__ __launch_bounds__(256) void agg_k(const __hip_bfloat16* __restrict__ h,
                                             const float* __restrict__ alp_s,
                                             const float* __restrict__ alp_d,
                                             const int* __restrict__ off,
                                             const int* __restrict__ slot,
                                             const float* __restrict__ bias,
                                             const float* __restrict__ gamma,
                                             const float* __restrict__ beta,
                                             const __hip_bfloat16* x_resb,
                                             float* x_out,
                                             __hip_bfloat16* x_out_b,
                                             float* __restrict__ zs,
                                             float* __restrict__ zd) {
    if (H == 8 && threadIdx.x < 4) {   // zero next layer's alpha accumulators (20000 = 5000 blk x 4)
        const int zi = blockIdx.x * 4 + threadIdx.x;
        if (zi < NN) { zs[zi] = 0.f; zd[zi] = 0.f; }
    }
    const int wid = threadIdx.x >> 6;
    const int lane = threadIdx.x & 63;
    const int n = blockIdx.x * 4 + wid;
    const int head = (H == 8) ? (lane >> 3) : 0;

    const int o0 = off[n];
    const int deg = off[n + 1] - o0;
    const int total = deg + 1;  // + self loop (virtual edge -> src = n)

    const float ad = (H == 8) ? alp_d[(size_t)n * 8 + head] : alp_d[n];

    // coalesced load of src list (+ self loop) into lanes, then 64-lane bitonic sort ascending
    int v = 0x7fffffff;
    if (lane < total && lane < 64) v = (lane < deg) ? slot[o0 + lane] : n;
#pragma unroll
    for (int k = 2; k <= 64; k <<= 1) {
#pragma unroll
        for (int j = k >> 1; j > 0; j >>= 1) {
            int o = __shfl_xor(v, j);
            bool takeMin = (((lane & k) == 0) == ((lane & j) == 0));
            v = takeMin ? min(v, o) : max(v, o);
        }
    }
    const int nsort = (total < 64) ? total : 64;

    float acc[8];
#pragma unroll
    for (int r = 0; r < 8; r++) acc[r] = 0.f;
    float ld = 0.f;
    const unsigned short* hu = (const unsigned short*)h;

    auto zcomp = [&](int s) -> float {
        float z = ((H == 8) ? alp_s[(size_t)s * 8 + head] : alp_s[s]) + ad;
        return (z >= 0.f) ? z : NEG_SLOPE * z;
    };
    auto fmarow = [&](const u32x4& rv, float p) {
#pragma unroll
        for (int q = 0; q < 4; q++) {
            unsigned int u = rv[q];
            acc[2 * q]     += p * __uint_as_float(u << 16);
            acc[2 * q + 1] += p * __uint_as_float(u & 0xffff0000u);
        }
    };

    int e = 0;
    for (; e + 4 <= nsort; e += 4) {
        const int s0 = __shfl(v, e), s1 = __shfl(v, e + 1);
        const int s2 = __shfl(v, e + 2), s3 = __shfl(v, e + 3);
        // issue all 4 row loads + 4 alpha loads before consuming
        const u32x4 r0 = *(const u32x4*)(hu + (size_t)s0 * DIM + lane * 8);
        const u32x4 r1 = *(const u32x4*)(hu + (size_t)s1 * DIM + lane * 8);
        const u32x4 r2 = *(const u32x4*)(hu + (size_t)s2 * DIM + lane * 8);
        const u32x4 r3 = *(const u32x4*)(hu + (size_t)s3 * DIM + lane * 8);
        const float z0 = zcomp(s0), z1 = zcomp(s1), z2 = zcomp(s2), z3 = zcomp(s3);
        const float p0 = __expf(z0), p1 = __expf(z1), p2 = __expf(z2), p3 = __expf(z3);
        ld += p0; fmarow(r0, p0);
        ld += p1; fmarow(r1, p1);
        ld += p2; fmarow(r2, p2);
        ld += p3; fmarow(r3, p3);
    }
    for (; e < nsort; e++) {
        const int s = __shfl(v, e);
        const u32x4 rv = *(const u32x4*)(hu + (size_t)s * DIM + lane * 8);
        const float p = __expf(zcomp(s));
        ld += p; fmarow(rv, p);
    }
    // rare tail: degree+1 > 64 (unsorted; includes self loop when deg >= 64)
    for (int e2 = 64; e2 < total; e2++) {
        const int s = (e2 < deg) ? slot[o0 + e2] : n;
        const u32x4 rv = *(const u32x4*)(hu + (size_t)s * DIM + lane * 8);
        const float p = __expf(zcomp(s));
        ld += p; fmarow(rv, p);
    }

    // normalize + bias (ld is already the full per-head denominator)
    const float inv = 1.f / ld;
    const int c0 = lane * 8;
    const float4 ba = *(const float4*)&bias[c0];
    const float4 bb = *(const float4*)&bias[c0 + 4];
    float xn[8];
    xn[0] = acc[0] * inv + ba.x; xn[1] = acc[1] * inv + ba.y;
    xn[2] = acc[2] * inv + ba.z; xn[3] = acc[3] * inv + ba.w;
    xn[4] = acc[4] * inv + bb.x; xn[5] = acc[5] * inv + bb.y;
    xn[6] = acc[6] * inv + bb.z; xn[7] = acc[7] * inv + bb.w;

    // LayerNorm stats: in-wave butterfly over 64 lanes
    float s1 = 0.f, s2 = 0.f;
#pragma unroll
    for (int r = 0; r < 8; r++) { s1 += xn[r]; s2 += xn[r] * xn[r]; }
#pragma unroll
    for (int o = 32; o; o >>= 1) { s1 += __shfl_xor(s1, o); s2 += __shfl_xor(s2, o); }
    const float mu = s1 * (1.f / DIM);
    const float rs = rsqrtf(s2 * (1.f / DIM) - mu * mu + LN_EPS);

    const float4 ga = *(const float4*)&gamma[c0];
    const float4 gb = *(const float4*)&gamma[c0 + 4];
    const float4 ea = *(const float4*)&beta[c0];
    const float4 eb = *(const float4*)&beta[c0 + 4];
    const bf16x8 xrv = *(const bf16x8*)&x_resb[(size_t)n * DIM + c0];
    const float gv[8] = {ga.x, ga.y, ga.z, ga.w, gb.x, gb.y, gb.z, gb.w};
    const float ev[8] = {ea.x, ea.y, ea.z, ea.w, eb.x, eb.y, eb.z, eb.w};

    float out[8];
#pragma unroll
    for (int r = 0; r < 8; r++) {
        float y = (xn[r] - mu) * rs * gv[r] + ev[r];
        y = (y > 0.f) ? y : expm1f(y);
        out[r] = bf2f(xrv[r]) + y;
    }
    if (x_out) {
        *(float4*)&x_out[(size_t)n * DIM + c0]     = make_float4(out[0], out[1], out[2], out[3]);
        *(float4*)&x_out[(size_t)n * DIM + c0 + 4] = make_float4(out[4], out[5], out[6], out[7]);
    }
    if (x_out_b) {  // fused fp32->bf16 for next layer's GEMM input + residual
        __hip_bfloat16 tb[8];
#pragma unroll
        for (int r = 0; r < 8; r++) tb[r] = __float2bfloat16(out[r]);
        *(bf16x8*)&x_out_b[(size_t)n * DIM + c0] = *(bf16x8*)tb;
    }
}

// ---------------- launch (7 dispatches; was 10) ----------------

extern "C" void kernel_launch(void* const* d_in, const int* in_sizes, int n_in,
                              void* d_out, int out_size, void* d_ws, size_t ws_size,
                              hipStream_t stream) {
    const float* x = (const float*)d_in[0];
    const int* ei = (const int*)d_in[1];   // int inputs arrive as int32
    const float* W1 = (const float*)d_in[2];
    const float* as1 = (const float*)d_in[3];
    const float* ad1 = (const float*)d_in[4];
    const float* b1 = (const float*)d_in[5];
    const float* g1 = (const float*)d_in[6];
    const float* be1 = (const float*)d_in[7];
    const float* W2 = (const float*)d_in[8];
    const float* as2 = (const float*)d_in[9];
    const float* ad2 = (const float*)d_in[10];
    const float* b2 = (const float*)d_in[11];
    const float* g2 = (const float*)d_in[12];
    const float* be2 = (const float*)d_in[13];
    float* out = (float*)d_out;

    char* ws = (char*)d_ws;
    size_t o = 0;
    auto alloc = [&](size_t bytes) { size_t r = o; o += (bytes + 255) & ~(size_t)255; return r; };
    int* p_cnt = (int*)(ws + alloc((size_t)NN * 4));
    int* p_off = (int*)(ws + alloc((size_t)(NN + 1) * 4));
    int* p_cur = (int*)(ws + alloc((size_t)NN * 4));
    int* p_slot = (int*)(ws + alloc((size_t)NE * 4));
    __hip_bfloat16* p_hb = (__hip_bfloat16*)(ws + alloc((size_t)NN * DIM * 2));  // h (bf16)
    __hip_bfloat16* p_xb = (__hip_bfloat16*)(ws + alloc((size_t)NN * DIM * 2));  // bf16 x / x1 (GEMM A + residual)
    __hip_bfloat16* p_bt1 = (__hip_bfloat16*)(ws + alloc((size_t)DIM * DIM * 2));
    __hip_bfloat16* p_bt2 = (__hip_bfloat16*)(ws + alloc((size_t)DIM * DIM * 2));
    float* p_as = (float*)(ws + alloc((size_t)NN * 8 * 4));    // H=8 alpha: [NN][8]
    float* p_ad = (float*)(ws + alloc((size_t)NN * 8 * 4));
    float* p_as2 = (float*)(ws + alloc((size_t)NN * 4));       // H=1 alpha: flat [NN] (atomic)
    float* p_ad2 = (float*)(ws + alloc((size_t)NN * 4));

    const int* e_src = ei;
    const int* e_dst = ei + NE;

    const int GB = 4 * ((NN + 127) / 128);   // 628 gemm blocks (col-slab fast via b&3)
    const int CB = (NE + 255) / 256;         // 1250 count/fill blocks

    // 1: conv x->bf16 + zero cnt + transpose W1,W2
    convz_k<<<NB_CONV + NB_ZERO + 512, 256, 0, stream>>>(x, p_xb, p_cnt, W1, W2, p_bt1, p_bt2);
    // 2: layer-1 GEMM + fused edge-count tail
    gemm_mfma<8><<<GB + CB, 256, 0, stream>>>((const short*)p_xb, (const short*)p_bt1, p_hb,
                                              as1, ad1, p_as, p_ad, NN, e_dst, p_cnt, GB);
    // 3-4: CSR offsets + fill
    scan_k<<<1, 1024, 0, stream>>>(p_cnt, p_off, p_cur);
    fill_k<<<CB, 256, 0, stream>>>(e_src, e_dst, p_cur, p_slot);
    // 5: layer-1 aggregation (+ zero p_as2/p_ad2 for gemm1's atomic epilogue)
    agg_k<8><<<NN / 4, 256, 0, stream>>>(p_hb, p_as, p_ad, p_off, p_slot, b1, g1, be1,
                                         p_xb, nullptr, p_xb, p_as2, p_ad2);
    // 6: layer-2 GEMM; alpha atomically accumulated into flat p_as2/p_ad2 (sum8_k eliminated)
    gemm_mfma<1><<<GB, 256, 0, stream>>>((const short*)p_xb, (const short*)p_bt2, p_hb,
                                         as2, ad2, p_as2, p_ad2, NN, nullptr, nullptr, GB);
    // 7: layer-2 aggregation -> final fp32 out
    agg_k<1><<<NN / 4, 256, 0, stream>>>(p_hb, p_as2, p_ad2, p_off, p_slot, b2, g2, be2,
                                         p_xb, out, nullptr, nullptr, nullptr);
}

// Round 9
// 309.204 us; speedup vs baseline: 1.2288x; 1.0048x over previous
//
#include <hip/hip_runtime.h>
#include <hip/hip_bf16.h>
#include <math.h>

#define NN 20000
#define NE 320000
#define DIM 512
#define LN_EPS 1e-5f
#define NEG_SLOPE 0.2f

typedef __attribute__((ext_vector_type(8))) short bf16x8;
typedef __attribute__((ext_vector_type(4))) float f32x4;
typedef __attribute__((ext_vector_type(4))) unsigned int u32x4;

__device__ inline void gload_lds16(const void* g, void* l) {
    __builtin_amdgcn_global_load_lds(
        (const __attribute__((address_space(1))) void*)g,
        (__attribute__((address_space(3))) void*)l, 16, 0, 0);
}

__device__ inline short f2bf(float f) {
    __hip_bfloat16 b = __float2bfloat16(f);
    return *reinterpret_cast<short*>(&b);
}

__device__ inline float bf2f(short u) {
    return __uint_as_float(((unsigned int)(unsigned short)u) << 16);
}

// ---------------- CSR build pieces (count is fused into gemm8's tail blocks) ----------------

__global__ __launch_bounds__(1024) void scan_k(const int* __restrict__ cnt,
                                               int* __restrict__ off,
                                               int* __restrict__ cur) {
    __shared__ int s[1024];
    const int t = threadIdx.x;
    const int lo = t * 20;
    int loc[20];
    int sum = 0;
#pragma unroll
    for (int i = 0; i < 20; i++) {
        int idx = lo + i;
        int v = (idx < NN) ? cnt[idx] : 0;
        loc[i] = v; sum += v;
    }
    s[t] = sum;
    __syncthreads();
    for (int o = 1; o < 1024; o <<= 1) {
        int x = (t >= o) ? s[t - o] : 0;
        __syncthreads();
        s[t] += x;
        __syncthreads();
    }
    int run = s[t] - sum;  // exclusive prefix
#pragma unroll
    for (int i = 0; i < 20; i++) {
        int idx = lo + i;
        if (idx < NN) { off[idx] = run; cur[idx] = run; run += loc[i]; }
    }
    if (t == 1023) off[NN] = s[1023];
}

__global__ void fill_k(const int* __restrict__ src, const int* __restrict__ dst,
                       int* __restrict__ cur, int* __restrict__ slot) {
    int e = blockIdx.x * blockDim.x + threadIdx.x;
    if (e < NE) {
        int d = dst[e];
        d = (d < 0) ? 0 : (d >= NN ? NN - 1 : d);
        int sv = src[e];
        sv = (sv < 0) ? 0 : (sv >= NN ? NN - 1 : sv);
        int p = atomicAdd(&cur[d], 1);
        slot[p] = sv;
    }
}

// ---------------- fused pre-pass: conv x->bf16 | zero cnt | transpose W1,W2 -> bf16 ----------------
// Flat grid: [0, NB_CONV) conv; [NB_CONV, NB_CONV+NB_ZERO) zero cnt; rest = 512 convT blocks.
#define NB_CONV 10000
#define NB_ZERO 20
__global__ __launch_bounds__(256) void convz_k(const float* __restrict__ in,
                                               __hip_bfloat16* __restrict__ out,
                                               int* __restrict__ cnt,
                                               const float* __restrict__ W1f,
                                               const float* __restrict__ W2f,
                                               __hip_bfloat16* __restrict__ B1,
                                               __hip_bfloat16* __restrict__ B2) {
    const int b = blockIdx.x;
    if (b < NB_CONV) {
        int i = (b * 256 + threadIdx.x) * 4;
        float4 v = *(const float4*)&in[i];
        out[i + 0] = __float2bfloat16(v.x);
        out[i + 1] = __float2bfloat16(v.y);
        out[i + 2] = __float2bfloat16(v.z);
        out[i + 3] = __float2bfloat16(v.w);
    } else if (b < NB_CONV + NB_ZERO) {
        int idx = (b - NB_CONV) * 256 + threadIdx.x;
        if (idx < NN / 4) ((int4*)cnt)[idx] = make_int4(0, 0, 0, 0);
    } else {
        // W[512][512] fp32 -> BT[n][k] bf16 (transpose); idx>>8 selects W1/W2
        const int idx = b - (NB_CONV + NB_ZERO);       // 0..511
        const int z = idx >> 8;
        const int rem = idx & 255;
        const int bk = (rem & 15) * 32, bn = (rem >> 4) * 32;
        const float* W = z ? W2f : W1f;
        __hip_bfloat16* BT = z ? B2 : B1;
        __shared__ float tile[32][33];
        const int tx = threadIdx.x & 31, ty = threadIdx.x >> 5;  // ty 0..7
#pragma unroll
        for (int i = 0; i < 32; i += 8)
            tile[ty + i][tx] = W[(size_t)(bk + ty + i) * DIM + bn + tx];
        __syncthreads();
#pragma unroll
        for (int i = 0; i < 32; i += 8)
            BT[(size_t)(bn + ty + i) * DIM + bk + tx] = __float2bfloat16(tile[tx][ty + i]);
    }
}

// ---------------- bf16 MFMA GEMM + fused alpha epilogue (R0 K-loop, unchanged) ----------------
// C[M,512] = A[M,512] @ B (B given as BT[n][k]). 128x128 tile, 4 waves, 4x4 of 16x16x32 MFMA.
// XCD-AWARE SWIZZLE (R9, T1): hardware round-robins blockIdx across the 8 XCDs, so the 4
// col-slab blocks sharing one A row-tile used to land on 4 DIFFERENT XCDs -> each private
// L2 fetched the A panel independently (A fill 4x = 82 MB; gemm was fabric-BW-bound at
// ~3.5-4 TB/s ~= 45 us). Bijective remap (m204): xcd = b&7 gets a CONTIGUOUS run of
// logical blocks -> all 4 sharers of a row-tile on one XCD; A fill ~1x, B L2-resident.
// Logical L: by = L>>2 (row-tile), bx = L&3 (col-slab).
// H=8 launch: blocks [gemmBlocks, +CB) are fused count_k tail (unswizzled, no LDS).
// H=1: alpha partial-dots atomicAdd into flat p_as/p_ad (zeroed by agg8).

template <int H>
__global__ __launch_bounds__(256) void gemm_mfma(const short* __restrict__ A,
                                                 const short* __restrict__ BT,
                                                 __hip_bfloat16* __restrict__ C,
                                                 const float* __restrict__ a_s,
                                                 const float* __restrict__ a_d,
                                                 float* __restrict__ p_as,
                                                 float* __restrict__ p_ad,
                                                 int M,
                                                 const int* __restrict__ e_dst,
                                                 int* __restrict__ cnt,
                                                 int gemmBlocks) {
    const int b = blockIdx.x;
    if (b >= gemmBlocks) {  // fused count_k tail (H=8 launch)
        int e = (b - gemmBlocks) * 256 + threadIdx.x;
        if (e < NE) {
            int d = e_dst[e];
            d = (d < 0) ? 0 : (d >= NN ? NN - 1 : d);
            atomicAdd(&cnt[d], 1);
        }
        return;
    }
    // bijective XCD swizzle: xcd x < r gets q+1 logical blocks, else q (contiguous runs)
    const int xq = gemmBlocks >> 3, xr = gemmBlocks & 7;
    const int xcd = b & 7, pos = b >> 3;
    const int L = (xcd < xr ? xcd * (xq + 1) : xr * (xq + 1) + (xcd - xr) * xq) + pos;
    const int bx = L & 3;                   // col-slab (FAST within an XCD's run)
    const int by = L >> 2;                  // row-tile

    __shared__ __align__(16) short SMEM[64 * 136];  // staging: As=4096, Bs=4096; epilogue: 64x136
    short* As = SMEM;
    short* Bs = SMEM + 4096;
    const int t = threadIdx.x;
    const int rowBase = by * 128;
    const int colBase = bx * 128;
    const int wave = t >> 6, lane = t & 63;
    const int wr = (wave >> 1) * 64;
    const int wc = (wave & 1) * 64;
    const int quad = lane >> 4, l16 = lane & 15;

    f32x4 acc[4][4];
#pragma unroll
    for (int i = 0; i < 4; i++)
#pragma unroll
        for (int j = 0; j < 4; j++) acc[i][j] = f32x4{0.f, 0.f, 0.f, 0.f};

    const int srow = t >> 2;
    const int skof = (t & 3) * 8;
    int ar0 = rowBase + srow;       if (ar0 > M - 1) ar0 = M - 1;
    int ar1 = rowBase + 64 + srow;  if (ar1 > M - 1) ar1 = M - 1;
    const int bn0 = colBase + srow;
    const int bn1 = colBase + 64 + srow;

    for (int k0 = 0; k0 < DIM; k0 += 32) {
        gload_lds16(A + (size_t)ar0 * DIM + k0 + skof, As + t * 8);
        gload_lds16(A + (size_t)ar1 * DIM + k0 + skof, As + 2048 + t * 8);
        gload_lds16(BT + (size_t)bn0 * DIM + k0 + skof, Bs + t * 8);
        gload_lds16(BT + (size_t)bn1 * DIM + k0 + skof, Bs + 2048 + t * 8);
        __syncthreads();

        bf16x8 af[4], bfr[4];
#pragma unroll
        for (int i = 0; i < 4; i++)
            af[i] = *(const bf16x8*)&As[(wr + i * 16 + l16) * 32 + quad * 8];
#pragma unroll
        for (int j = 0; j < 4; j++)
            bfr[j] = *(const bf16x8*)&Bs[(wc + j * 16 + l16) * 32 + quad * 8];
#pragma unroll
        for (int i = 0; i < 4; i++)
#pragma unroll
            for (int j = 0; j < 4; j++)
                acc[i][j] = __builtin_amdgcn_mfma_f32_16x16x32_bf16(af[i], bfr[j], acc[i][j], 0, 0, 0);
        __syncthreads();
    }

    // ---- C store via LDS staging: pass p covers rows [64p, 64p+64)
#pragma unroll
    for (int p = 0; p < 2; p++) {
        if ((wave >> 1) == p) {
#pragma unroll
            for (int i = 0; i < 4; i++)
#pragma unroll
                for (int j = 0; j < 4; j++)
#pragma unroll
                    for (int r = 0; r < 4; r++)
                        SMEM[(i * 16 + quad * 4 + r) * 136 + wc + j * 16 + l16] =
                            f2bf(acc[i][j][r]);
        }
        __syncthreads();
#pragma unroll
        for (int k = 0; k < 4; k++) {
            const int row = k * 16 + (t >> 4);
            const int col = (t & 15) * 8;
            const int gr = rowBase + p * 64 + row;
            if (gr < M) {
                bf16x8 vv = *(const bf16x8*)&SMEM[row * 136 + col];
                *(bf16x8*)&C[(size_t)gr * DIM + colBase + col] = vv;
            }
        }
        __syncthreads();
    }

    // ---- alpha epilogue: dot of this wave's 64-col slab with a_s/a_d coefficients
    const int slab = 2 * bx + (wave & 1);                       // head id (H=8)
    const int cb = (H == 8) ? slab * 64 : (colBase + wc);       // coefficient base (equal values)
    float asc[4], adc[4];
#pragma unroll
    for (int j = 0; j < 4; j++) {
        asc[j] = a_s[cb + j * 16 + l16];
        adc[j] = a_d[cb + j * 16 + l16];
    }
#pragma unroll
    for (int i = 0; i < 4; i++) {
#pragma unroll
        for (int r = 0; r < 4; r++) {
            float vs = acc[i][0][r] * asc[0] + acc[i][1][r] * asc[1] +
                       acc[i][2][r] * asc[2] + acc[i][3][r] * asc[3];
            float vd = acc[i][0][r] * adc[0] + acc[i][1][r] * adc[1] +
                       acc[i][2][r] * adc[2] + acc[i][3][r] * adc[3];
#pragma unroll
            for (int o = 8; o; o >>= 1) { vs += __shfl_down(vs, o); vd += __shfl_down(vd, o); }
            if (l16 == 0) {
                const int row = rowBase + wr + i * 16 + quad * 4 + r;
                if (row < M) {
                    if (H == 8) {
                        p_as[(size_t)row * 8 + slab] = vs;
                        p_ad[(size_t)row * 8 + slab] = vd;
                    } else {
                        atomicAdd(&p_as[row], vs);
                        atomicAdd(&p_ad[row], vd);
                    }
                }
            }
        }
    }
}

// ---------------- fused aggregation: ONE WAVE PER NODE (h in bf16) ----------------
// Main loop = EXACT R0 structure (6 rounds reproduced at its L2-miss-traffic floor).
// R7 epilogue: residual read as bf16 from p_xb; L1 writes ONLY bf16 (into p_xb).
// H=8 extra: 4 threads/block zero p_as2/p_ad2 for gemm1's atomic alpha epilogue.
// DO NOT TOUCH the edge loop.

template <int H>
__global__ __launch_bounds__(256) void agg_k(const __hip_bfloat16* __restrict__ h,
                                             const float* __restrict__ alp_s,
                                             const float* __restrict__ alp_d,
                                             const int* __restrict__ off,
                                             const int* __restrict__ slot,
                                             const float* __restrict__ bias,
                                             const float* __restrict__ gamma,
                                             const float* __restrict__ beta,
                                             const __hip_bfloat16* x_resb,
                                             float* x_out,
                                             __hip_bfloat16* x_out_b,
                                             float* __restrict__ zs,
                                             float* __restrict__ zd) {
    if (H == 8 && threadIdx.x < 4) {   // zero next layer's alpha accumulators (20000 = 5000 blk x 4)
        const int zi = blockIdx.x * 4 + threadIdx.x;
        if (zi < NN) { zs[zi] = 0.f; zd[zi] = 0.f; }
    }
    const int wid = threadIdx.x >> 6;
    const int lane = threadIdx.x & 63;
    const int n = blockIdx.x * 4 + wid;
    const int head = (H == 8) ? (lane >> 3) : 0;

    const int o0 = off[n];
    const int deg = off[n + 1] - o0;
    const int total = deg + 1;  // + self loop (virtual edge -> src = n)

    const float ad = (H == 8) ? alp_d[(size_t)n * 8 + head] : alp_d[n];

    // coalesced load of src list (+ self loop) into lanes, then 64-lane bitonic sort ascending
    int v = 0x7fffffff;
    if (lane < total && lane < 64) v = (lane < deg) ? slot[o0 + lane] : n;
#pragma unroll
    for (int k = 2; k <= 64; k <<= 1) {
#pragma unroll
        for (int j = k >> 1; j > 0; j >>= 1) {
            int o = __shfl_xor(v, j);
            bool takeMin = (((lane & k) == 0) == ((lane & j) == 0));
            v = takeMin ? min(v, o) : max(v, o);
        }
    }
    const int nsort = (total < 64) ? total : 64;

    float acc[8];
#pragma unroll
    for (int r = 0; r < 8; r++) acc[r] = 0.f;
    float ld = 0.f;
    const unsigned short* hu = (const unsigned short*)h;

    auto zcomp = [&](int s) -> float {
        float z = ((H == 8) ? alp_s[(size_t)s * 8 + head] : alp_s[s]) + ad;
        return (z >= 0.f) ? z : NEG_SLOPE * z;
    };
    auto fmarow = [&](const u32x4& rv, float p) {
#pragma unroll
        for (int q = 0; q < 4; q++) {
            unsigned int u = rv[q];
            acc[2 * q]     += p * __uint_as_float(u << 16);
            acc[2 * q + 1] += p * __uint_as_float(u & 0xffff0000u);
        }
    };

    int e = 0;
    for (; e + 4 <= nsort; e += 4) {
        const int s0 = __shfl(v, e), s1 = __shfl(v, e + 1);
        const int s2 = __shfl(v, e + 2), s3 = __shfl(v, e + 3);
        // issue all 4 row loads + 4 alpha loads before consuming
        const u32x4 r0 = *(const u32x4*)(hu + (size_t)s0 * DIM + lane * 8);
        const u32x4 r1 = *(const u32x4*)(hu + (size_t)s1 * DIM + lane * 8);
        const u32x4 r2 = *(const u32x4*)(hu + (size_t)s2 * DIM + lane * 8);
        const u32x4 r3 = *(const u32x4*)(hu + (size_t)s3 * DIM + lane * 8);
        const float z0 = zcomp(s0), z1 = zcomp(s1), z2 = zcomp(s2), z3 = zcomp(s3);
        const float p0 = __expf(z0), p1 = __expf(z1), p2 = __expf(z2), p3 = __expf(z3);
        ld += p0; fmarow(r0, p0);
        ld += p1; fmarow(r1, p1);
        ld += p2; fmarow(r2, p2);
        ld += p3; fmarow(r3, p3);
    }
    for (; e < nsort; e++) {
        const int s = __shfl(v, e);
        const u32x4 rv = *(const u32x4*)(hu + (size_t)s * DIM + lane * 8);
        const float p = __expf(zcomp(s));
        ld += p; fmarow(rv, p);
    }
    // rare tail: degree+1 > 64 (unsorted; includes self loop when deg >= 64)
    for (int e2 = 64; e2 < total; e2++) {
        const int s = (e2 < deg) ? slot[o0 + e2] : n;
        const u32x4 rv = *(const u32x4*)(hu + (size_t)s * DIM + lane * 8);
        const float p = __expf(zcomp(s));
        ld += p; fmarow(rv, p);
    }

    // normalize + bias (ld is already the full per-head denominator)
    const float inv = 1.f / ld;
    const int c0 = lane * 8;
    const float4 ba = *(const float4*)&bias[c0];
    const float4 bb = *(const float4*)&bias[c0 + 4];
    float xn[8];
    xn[0] = acc[0] * inv + ba.x; xn[1] = acc[1] * inv + ba.y;
    xn[2] = acc[2] * inv + ba.z; xn[3] = acc[3] * inv + ba.w;
    xn[4] = acc[4] * inv + bb.x; xn[5] = acc[5] * inv + bb.y;
    xn[6] = acc[6] * inv + bb.z; xn[7] = acc[7] * inv + bb.w;

    // LayerNorm stats: in-wave butterfly over 64 lanes
    float s1 = 0.f, s2 = 0.f;
#pragma unroll
    for (int r = 0; r < 8; r++) { s1 += xn[r]; s2 += xn[r] * xn[r]; }
#pragma unroll
    for (int o = 32; o; o >>= 1) { s1 += __shfl_xor(s1, o); s2 += __shfl_xor(s2, o); }
    const float mu = s1 * (1.f / DIM);
    const float rs = rsqrtf(s2 * (1.f / DIM) - mu * mu + LN_EPS);

    const float4 ga = *(const float4*)&gamma[c0];
    const float4 gb = *(const float4*)&gamma[c0 + 4];
    const float4 ea = *(const float4*)&beta[c0];
    const float4 eb = *(const float4*)&beta[c0 + 4];
    const bf16x8 xrv = *(const bf16x8*)&x_resb[(size_t)n * DIM + c0];
    const float gv[8] = {ga.x, ga.y, ga.z, ga.w, gb.x, gb.y, gb.z, gb.w};
    const float ev[8] = {ea.x, ea.y, ea.z, ea.w, eb.x, eb.y, eb.z, eb.w};

    float out[8];
#pragma unroll
    for (int r = 0; r < 8; r++) {
        float y = (xn[r] - mu) * rs * gv[r] + ev[r];
        y = (y > 0.f) ? y : expm1f(y);
        out[r] = bf2f(xrv[r]) + y;
    }
    if (x_out) {
        *(float4*)&x_out[(size_t)n * DIM + c0]     = make_float4(out[0], out[1], out[2], out[3]);
        *(float4*)&x_out[(size_t)n * DIM + c0 + 4] = make_float4(out[4], out[5], out[6], out[7]);
    }
    if (x_out_b) {  // fused fp32->bf16 for next layer's GEMM input + residual
        __hip_bfloat16 tb[8];
#pragma unroll
        for (int r = 0; r < 8; r++) tb[r] = __float2bfloat16(out[r]);
        *(bf16x8*)&x_out_b[(size_t)n * DIM + c0] = *(bf16x8*)tb;
    }
}

// ---------------- launch (7 dispatches) ----------------

extern "C" void kernel_launch(void* const* d_in, const int* in_sizes, int n_in,
                              void* d_out, int out_size, void* d_ws, size_t ws_size,
                              hipStream_t stream) {
    const float* x = (const float*)d_in[0];
    const int* ei = (const int*)d_in[1];   // int inputs arrive as int32
    const float* W1 = (const float*)d_in[2];
    const float* as1 = (const float*)d_in[3];
    const float* ad1 = (const float*)d_in[4];
    const float* b1 = (const float*)d_in[5];
    const float* g1 = (const float*)d_in[6];
    const float* be1 = (const float*)d_in[7];
    const float* W2 = (const float*)d_in[8];
    const float* as2 = (const float*)d_in[9];
    const float* ad2 = (const float*)d_in[10];
    const float* b2 = (const float*)d_in[11];
    const float* g2 = (const float*)d_in[12];
    const float* be2 = (const float*)d_in[13];
    float* out = (float*)d_out;

    char* ws = (char*)d_ws;
    size_t o = 0;
    auto alloc = [&](size_t bytes) { size_t r = o; o += (bytes + 255) & ~(size_t)255; return r; };
    int* p_cnt = (int*)(ws + alloc((size_t)NN * 4));
    int* p_off = (int*)(ws + alloc((size_t)(NN + 1) * 4));
    int* p_cur = (int*)(ws + alloc((size_t)NN * 4));
    int* p_slot = (int*)(ws + alloc((size_t)NE * 4));
    __hip_bfloat16* p_hb = (__hip_bfloat16*)(ws + alloc((size_t)NN * DIM * 2));  // h (bf16)
    __hip_bfloat16* p_xb = (__hip_bfloat16*)(ws + alloc((size_t)NN * DIM * 2));  // bf16 x / x1 (GEMM A + residual)
    __hip_bfloat16* p_bt1 = (__hip_bfloat16*)(ws + alloc((size_t)DIM * DIM * 2));
    __hip_bfloat16* p_bt2 = (__hip_bfloat16*)(ws + alloc((size_t)DIM * DIM * 2));
    float* p_as = (float*)(ws + alloc((size_t)NN * 8 * 4));    // H=8 alpha: [NN][8]
    float* p_ad = (float*)(ws + alloc((size_t)NN * 8 * 4));
    float* p_as2 = (float*)(ws + alloc((size_t)NN * 4));       // H=1 alpha: flat [NN] (atomic)
    float* p_ad2 = (float*)(ws + alloc((size_t)NN * 4));

    const int* e_src = ei;
    const int* e_dst = ei + NE;

    const int GB = 4 * ((NN + 127) / 128);   // 628 gemm blocks (XCD-swizzled in-kernel)
    const int CB = (NE + 255) / 256;         // 1250 count/fill blocks

    // 1: conv x->bf16 + zero cnt + transpose W1,W2
    convz_k<<<NB_CONV + NB_ZERO + 512, 256, 0, stream>>>(x, p_xb, p_cnt, W1, W2, p_bt1, p_bt2);
    // 2: layer-1 GEMM + fused edge-count tail
    gemm_mfma<8><<<GB + CB, 256, 0, stream>>>((const short*)p_xb, (const short*)p_bt1, p_hb,
                                              as1, ad1, p_as, p_ad, NN, e_dst, p_cnt, GB);
    // 3-4: CSR offsets + fill
    scan_k<<<1, 1024, 0, stream>>>(p_cnt, p_off, p_cur);
    fill_k<<<CB, 256, 0, stream>>>(e_src, e_dst, p_cur, p_slot);
    // 5: layer-1 aggregation (+ zero p_as2/p_ad2 for gemm1's atomic epilogue)
    agg_k<8><<<NN / 4, 256, 0, stream>>>(p_hb, p_as, p_ad, p_off, p_slot, b1, g1, be1,
                                         p_xb, nullptr, p_xb, p_as2, p_ad2);
    // 6: layer-2 GEMM; alpha atomically accumulated into flat p_as2/p_ad2
    gemm_mfma<1><<<GB, 256, 0, stream>>>((const short*)p_xb, (const short*)p_bt2, p_hb,
                                         as2, ad2, p_as2, p_ad2, NN, nullptr, nullptr, GB);
    // 7: layer-2 aggregation -> final fp32 out
    agg_k<1><<<NN / 4, 256, 0, stream>>>(p_hb, p_as2, p_ad2, p_off, p_slot, b2, g2, be2,
                                         p_xb, out, nullptr, nullptr, nullptr);
}